// Round 2
// baseline (12812.509 us; speedup 1.0000x reference)
//
#include <hip/hip_runtime.h>
#include <math.h>

// Fixed problem geometry (complete digraph per 23-node graph)
#define NNODES 11776
#define NGR    512
#define NPG    23
#define FDIM   128
#define HID    32
#define CDIM   256
#define JKH    896
#define ZCOLS  3584      // 4*JKH
#define EPSBN  1e-5f

typedef long long i64;

__device__ __forceinline__ float sigmoidf_(float x) { return 1.f / (1.f + expf(-x)); }

// ---------------------------------------------------------------------------
// Stage 1: positional encoding + Conv1d(23->23, k=3, pad=1) over feature axis
// ---------------------------------------------------------------------------
__global__ __launch_bounds__(256) void conv1_kernel(
    const float* __restrict__ x, const float* __restrict__ w,
    const float* __restrict__ bias, float* __restrict__ out) {
  int b = blockIdx.x;
  __shared__ float in[NPG][FDIM];
  __shared__ float wsh[NPG * NPG * 3];
  int tid = threadIdx.x;
  const float c0 = -2.f * logf(10000.f) / 23.f;
  for (int idx = tid; idx < NPG * FDIM; idx += 256) {
    int p = idx >> 7, f = idx & 127;
    int j = p >> 1;
    float ang = (float)f * expf(c0 * (float)j);
    float pe = (p & 1) ? cosf(ang) : sinf(ang);
    in[p][f] = x[(i64)(b * NPG + p) * FDIM + f] + pe;
  }
  for (int idx = tid; idx < NPG * NPG * 3; idx += 256) wsh[idx] = w[idx];
  __syncthreads();
  for (int idx = tid; idx < NPG * FDIM; idx += 256) {
    int o = idx >> 7, f = idx & 127;
    float acc = bias[o];
    for (int i = 0; i < NPG; ++i) {
      const float* wr = &wsh[(o * NPG + i) * 3];
      float s = in[i][f] * wr[1];
      if (f > 0)   s += in[i][f - 1] * wr[0];
      if (f < 127) s += in[i][f + 1] * wr[2];
      acc += s;
    }
    out[(i64)(b * NPG + o) * FDIM + f] = acc;
  }
}

// ---------------------------------------------------------------------------
// Column statistics: acc[c] += sum(X[:,c]), acc[cols+c] += sum(X[:,c]^2)
// cols must divide 256. acc must be pre-zeroed.
// ---------------------------------------------------------------------------
__global__ __launch_bounds__(256) void col_stats(
    const float* __restrict__ X, int rows, int cols, float* __restrict__ acc) {
  int rpt = 256 / cols;
  int c = threadIdx.x % cols;
  int rsub = threadIdx.x / cols;
  float s = 0.f, q = 0.f;
  for (int r0 = blockIdx.x * rpt; r0 < rows; r0 += gridDim.x * rpt) {
    int r = r0 + rsub;
    if (r < rows) {
      float v = X[(i64)r * cols + c];
      s += v; q += v * v;
    }
  }
  __shared__ float sh[256];
  sh[threadIdx.x] = s;
  __syncthreads();
  if (threadIdx.x < cols) {
    float t = 0.f;
    for (int g = 0; g < rpt; ++g) t += sh[g * cols + c];
    atomicAdd(&acc[c], t);
  }
  __syncthreads();
  sh[threadIdx.x] = q;
  __syncthreads();
  if (threadIdx.x < cols) {
    float t = 0.f;
    for (int g = 0; g < rpt; ++g) t += sh[g * cols + c];
    atomicAdd(&acc[cols + c], t);
  }
}

// BN (affine=False), training mode, biased variance
__global__ void bn_norm(const float* __restrict__ X, float* __restrict__ Y,
                        const float* __restrict__ acc, int rows, int cols) {
  i64 total = (i64)rows * cols;
  i64 idx = (i64)blockIdx.x * 256 + threadIdx.x;
  i64 stride = (i64)gridDim.x * 256;
  float invR = 1.f / (float)rows;
  for (; idx < total; idx += stride) {
    int c = (int)(idx % cols);
    float mu = acc[c] * invR;
    float var = acc[cols + c] * invR - mu * mu;
    Y[idx] = (X[idx] - mu) * rsqrtf(var + EPSBN);
  }
}

// Fold BN1(affine) into ll1
__global__ __launch_bounds__(256) void fold_ll1(
    const float* __restrict__ acc, const float* __restrict__ g,
    const float* __restrict__ be, const float* __restrict__ w,
    const float* __restrict__ lb, float* __restrict__ Wp, float* __restrict__ bp) {
  int tid = threadIdx.x;
  const float invR = 1.f / (float)NNODES;
  for (int idx = tid; idx < FDIM * HID; idx += 256) {
    int k = idx >> 5;
    float mu = acc[k] * invR;
    float var = acc[FDIM + k] * invR - mu * mu;
    float scale = g[k] * rsqrtf(var + EPSBN);
    Wp[idx] = scale * w[idx];
  }
  if (tid < HID) {
    float s = lb[tid];
    for (int k = 0; k < FDIM; ++k) {
      float mu = acc[k] * invR;
      float var = acc[FDIM + k] * invR - mu * mu;
      float scale = g[k] * rsqrtf(var + EPSBN);
      s += (be[k] - mu * scale) * w[k * HID + tid];
    }
    bp[tid] = s;
  }
}

// ---------------------------------------------------------------------------
// SGEMM: C[M,N] = A[M,K] * B (+epilogue). BT=0: B is [K,N]; BT=1: B is [N,K].
// 128x128x16 tile, 256 threads, 8x8 micro-tile. M multiple of 128 (grid.x
// covers it), K multiple of 16; N guarded.
// ---------------------------------------------------------------------------
template <int BT>
__global__ __launch_bounds__(256) void sgemm(
    const float* __restrict__ A, const float* __restrict__ B, float* __restrict__ C,
    int M, int N, int K,
    const float* __restrict__ bias, const float* __restrict__ resid,
    int act, int accumulate) {
  __shared__ float As[16][128];   // [k][m]
  __shared__ float Bs[16][128];   // [k][n]
  int tid = threadIdx.x;
  int bm0 = blockIdx.x * 128;
  int bn0 = blockIdx.y * 128;
  int tx = tid & 15, ty = tid >> 4;
  float acc[8][8];
#pragma unroll
  for (int i = 0; i < 8; ++i)
#pragma unroll
    for (int j = 0; j < 8; ++j) acc[i][j] = 0.f;

  int ar = tid >> 2;            // 0..63
  int akc = (tid & 3) << 2;     // 0,4,8,12
  bool bfull = (bn0 + 127 < N);

  for (int k0 = 0; k0 < K; k0 += 16) {
    {
      const float* ap = A + (i64)(bm0 + ar) * K + k0 + akc;
      float4 a0 = *(const float4*)ap;
      float4 a1 = *(const float4*)(ap + (i64)64 * K);
      As[akc + 0][ar] = a0.x; As[akc + 1][ar] = a0.y;
      As[akc + 2][ar] = a0.z; As[akc + 3][ar] = a0.w;
      As[akc + 0][ar + 64] = a1.x; As[akc + 1][ar + 64] = a1.y;
      As[akc + 2][ar + 64] = a1.z; As[akc + 3][ar + 64] = a1.w;
    }
    if (BT) {
      int br = tid >> 1;            // 0..127 (n)
      int bkc = (tid & 1) << 3;     // 0 or 8
      const float* bp = B + (i64)(bn0 + br) * K + k0 + bkc;
      float4 b0 = *(const float4*)bp;
      float4 b1 = *(const float4*)(bp + 4);
      Bs[bkc + 0][br] = b0.x; Bs[bkc + 1][br] = b0.y;
      Bs[bkc + 2][br] = b0.z; Bs[bkc + 3][br] = b0.w;
      Bs[bkc + 4][br] = b1.x; Bs[bkc + 5][br] = b1.y;
      Bs[bkc + 6][br] = b1.z; Bs[bkc + 7][br] = b1.w;
    } else {
      int bk = tid >> 4;            // 0..15 (k)
      int bn = (tid & 15) << 3;     // 0..120 (n)
      const float* bp = B + (i64)(k0 + bk) * N + bn0 + bn;
      if (bfull) {
        float4 b0 = *(const float4*)bp;
        float4 b1 = *(const float4*)(bp + 4);
        *(float4*)&Bs[bk][bn] = b0;
        *(float4*)&Bs[bk][bn + 4] = b1;
      } else {
#pragma unroll
        for (int q = 0; q < 8; ++q)
          Bs[bk][bn + q] = (bn0 + bn + q < N) ? bp[q] : 0.f;
      }
    }
    __syncthreads();
#pragma unroll
    for (int kk = 0; kk < 16; ++kk) {
      float a[8], b[8];
      *(float4*)(a)     = *(const float4*)&As[kk][ty * 8];
      *(float4*)(a + 4) = *(const float4*)&As[kk][ty * 8 + 4];
      *(float4*)(b)     = *(const float4*)&Bs[kk][tx * 8];
      *(float4*)(b + 4) = *(const float4*)&Bs[kk][tx * 8 + 4];
#pragma unroll
      for (int i = 0; i < 8; ++i)
#pragma unroll
        for (int j = 0; j < 8; ++j)
          acc[i][j] = fmaf(a[i], b[j], acc[i][j]);
    }
    __syncthreads();
  }
#pragma unroll
  for (int i = 0; i < 8; ++i) {
    int m = bm0 + ty * 8 + i;
#pragma unroll
    for (int j = 0; j < 8; ++j) {
      int n = bn0 + tx * 8 + j;
      if (n < N) {
        i64 ci = (i64)m * N + n;
        float v = acc[i][j];
        if (accumulate) {
          C[ci] += v;
        } else {
          if (bias) v += bias[n];
          if (act == 1) v = v > 0.f ? v : expm1f(v);
          if (resid) v += resid[ci];
          C[ci] = v;
        }
      }
    }
  }
}

// ---------------------------------------------------------------------------
// TAGConv propagation: (A x)[v] = (S - x[v]) / 22 with group-sum S invariant
// ---------------------------------------------------------------------------
__global__ __launch_bounds__(256) void tagprop(const float* __restrict__ h,
                                               float* __restrict__ feats) {
  int b = blockIdx.x;
  __shared__ float hsh[NPG * HID];
  __shared__ float S[HID];
  int tid = threadIdx.x;
  const float* hp = h + (i64)b * NPG * HID;
  for (int idx = tid; idx < NPG * HID; idx += 256) hsh[idx] = hp[idx];
  __syncthreads();
  if (tid < HID) {
    float s = 0.f;
    for (int p = 0; p < NPG; ++p) s += hsh[p * HID + tid];
    S[tid] = s;
  }
  __syncthreads();
  float dinv = rsqrtf(22.f);
  float wn = dinv * dinv;
  for (int idx = tid; idx < NPG * HID; idx += 256) {
    int p = idx >> 5, c = idx & 31;
    float f0 = hsh[idx];
    float Sc = S[c];
    float f1 = (Sc - f0) * wn;
    float f2 = (Sc - f1) * wn;
    float f3 = (Sc - f2) * wn;
    float* row = feats + (i64)(b * NPG + p) * FDIM;
    row[c] = f0;
    row[HID + c] = f1;
    row[2 * HID + c] = f2;
    row[3 * HID + c] = f3;
  }
}

// ---------------------------------------------------------------------------
// GAT layer (8 heads x 32 dims), dense 23x23 attention per group incl. self-loop
// ---------------------------------------------------------------------------
__global__ __launch_bounds__(256) void gat_kernel(
    const float* __restrict__ g, const float* __restrict__ asrc,
    const float* __restrict__ adst, const float* __restrict__ gbias,
    float* __restrict__ outseq) {
  int b = blockIdx.x;
  __shared__ float gsh[NPG * CDIM];
  __shared__ float ssrc[NPG * 8], sdst[NPG * 8], sinv[NPG * 8];
  __shared__ float ealpha[NPG * NPG * 8];
  int tid = threadIdx.x;
  const i64 base = (i64)b * NPG * CDIM;
  for (int idx = tid; idx < NPG * CDIM; idx += 256) gsh[idx] = g[base + idx];
  __syncthreads();
  if (tid < NPG * 8) {
    int p = tid >> 3, hd = tid & 7;
    float s1 = 0.f, s2 = 0.f;
    const float* gp = &gsh[p * CDIM + hd * 32];
#pragma unroll
    for (int d = 0; d < 32; ++d) {
      s1 += gp[d] * asrc[hd * 32 + d];
      s2 += gp[d] * adst[hd * 32 + d];
    }
    ssrc[tid] = s1;
    sdst[tid] = s2;
  }
  __syncthreads();
  if (tid < NPG * 8) {
    int v = tid >> 3, hd = tid & 7;
    float sd = sdst[v * 8 + hd];
    float e[NPG];
    float m = -1e30f;
#pragma unroll
    for (int u = 0; u < NPG; ++u) {
      float xv = ssrc[u * 8 + hd] + sd;
      xv = xv > 0.f ? xv : 0.2f * xv;   // leaky_relu 0.2
      e[u] = xv;
      m = fmaxf(m, xv);
    }
    float s = 0.f;
#pragma unroll
    for (int u = 0; u < NPG; ++u) {
      float t = expf(e[u] - m);
      ealpha[(v * NPG + u) * 8 + hd] = t;
      s += t;
    }
    sinv[tid] = 1.f / s;
  }
  __syncthreads();
  {
    int hd = tid >> 5, d = tid & 31;
    for (int v = 0; v < NPG; ++v) {
      float acc = 0.f;
#pragma unroll
      for (int u = 0; u < NPG; ++u)
        acc += ealpha[(v * NPG + u) * 8 + hd] * gsh[u * CDIM + hd * 32 + d];
      outseq[base + (i64)v * CDIM + hd * 32 + d] =
          acc * sinv[v * 8 + hd] + gbias[hd * 32 + d];
    }
  }
}

// ---------------------------------------------------------------------------
// LSTM pieces (row-chunked; rows = chunk row count)
// ---------------------------------------------------------------------------
__global__ void add2(const float* __restrict__ a, const float* __restrict__ b,
                     float* __restrict__ o, int n) {
  int i = blockIdx.x * 256 + threadIdx.x;
  if (i < n) o[i] = a[i] + b[i];
}

__global__ void fill0(float* __restrict__ p, i64 nfloat) {
  i64 i = (i64)blockIdx.x * 256 + threadIdx.x;
  i64 stride = (i64)gridDim.x * 256;
  for (; i < nfloat; i += stride) p[i] = 0.f;
}

// z layout [rows, 3584] = [i | f | g | o] chunks of 896 (torch gate order)
__global__ __launch_bounds__(256) void lstm_gates(
    const float* __restrict__ z, float* __restrict__ c, float* __restrict__ h,
    int rows) {
  i64 idx = (i64)blockIdx.x * 256 + threadIdx.x;
  if (idx >= (i64)rows * JKH) return;
  i64 n = idx / JKH;
  int j = (int)(idx - n * JKH);
  const float* zr = z + n * ZCOLS;
  float zi = zr[j], zf = zr[JKH + j], zg = zr[2 * JKH + j], zo = zr[3 * JKH + j];
  float cv = sigmoidf_(zf) * c[idx] + sigmoidf_(zi) * tanhf(zg);
  c[idx] = cv;
  h[idx] = sigmoidf_(zo) * tanhf(cv);
}

// out[n] = dot(h[n,:], jkw[0:896])
__global__ __launch_bounds__(256) void att_dot(const float* __restrict__ H,
                                               const float* __restrict__ jkw,
                                               float* __restrict__ out) {
  int n = blockIdx.x;
  const float* h = H + (i64)n * JKH;
  float s = 0.f;
  for (int j = threadIdx.x; j < JKH; j += 256) s += h[j] * jkw[j];
  __shared__ float sh[4];
#pragma unroll
  for (int o = 32; o > 0; o >>= 1) s += __shfl_down(s, o, 64);
  if ((threadIdx.x & 63) == 0) sh[threadIdx.x >> 6] = s;
  __syncthreads();
  if (threadIdx.x == 0) out[n] = sh[0] + sh[1] + sh[2] + sh[3];
}

// softmax over the 5 layers, weighted sum of seq -> xg  (jk_b cancels)
__global__ __launch_bounds__(256) void jk_combine(const float* __restrict__ att,
                                                  const float* __restrict__ seq,
                                                  float* __restrict__ xg) {
  int n = blockIdx.x, c = threadIdx.x;
  float a[5];
  float m = -1e30f;
#pragma unroll
  for (int t = 0; t < 5; ++t) {
    a[t] = att[(i64)t * NNODES + n] + att[(i64)(5 + t) * NNODES + n];
    m = fmaxf(m, a[t]);
  }
  float s = 0.f;
#pragma unroll
  for (int t = 0; t < 5; ++t) { a[t] = expf(a[t] - m); s += a[t]; }
  float inv = 1.f / s;
  float acc = 0.f;
#pragma unroll
  for (int t = 0; t < 5; ++t)
    acc += seq[((i64)t * NNODES + n) * CDIM + c] * (a[t] * inv);
  xg[(i64)n * CDIM + c] = acc;
}

// gate = xg @ (gate_w1 @ gate_w2) + (gate_b1 . gate_w2 + gate_b2)
__global__ __launch_bounds__(256) void fold_gate(
    const float* __restrict__ w1, const float* __restrict__ b1,
    const float* __restrict__ w2, const float* __restrict__ b2,
    float* __restrict__ v, float* __restrict__ b0) {
  int tid = threadIdx.x;
  float s = 0.f;
  for (int j = 0; j < 672; ++j) s += w1[tid * 672 + j] * w2[j];
  v[tid] = s;
  float p = 0.f;
  for (int j = tid; j < 672; j += 256) p += b1[j] * w2[j];
  __shared__ float sh[4];
#pragma unroll
  for (int o = 32; o > 0; o >>= 1) p += __shfl_down(p, o, 64);
  if ((tid & 63) == 0) sh[tid >> 6] = p;
  __syncthreads();
  if (tid == 0) b0[0] = sh[0] + sh[1] + sh[2] + sh[3] + b2[0];
}

// GlobalAttention pooling per graph (softmax over 23 nodes)
__global__ __launch_bounds__(256) void pool_kernel(
    const float* __restrict__ xgn, const float* __restrict__ v,
    const float* __restrict__ b0, float* __restrict__ pooled) {
  int g = blockIdx.x, tid = threadIdx.x;
  __shared__ float gw[NPG];
  __shared__ float sh[4];
  float myv = v[tid];
  for (int p = 0; p < NPG; ++p) {
    float val = xgn[(i64)(g * NPG + p) * CDIM + tid] * myv;
#pragma unroll
    for (int o = 32; o > 0; o >>= 1) val += __shfl_down(val, o, 64);
    if ((tid & 63) == 0) sh[tid >> 6] = val;
    __syncthreads();
    if (tid == 0) gw[p] = sh[0] + sh[1] + sh[2] + sh[3] + b0[0];
    __syncthreads();
  }
  if (tid == 0) {
    float m = -1e30f;
    for (int p = 0; p < NPG; ++p) m = fmaxf(m, gw[p]);
    float s = 0.f;
    for (int p = 0; p < NPG; ++p) { gw[p] = expf(gw[p] - m); s += gw[p]; }
    float inv = 1.f / s;
    for (int p = 0; p < NPG; ++p) gw[p] *= inv;
  }
  __syncthreads();
  float acc = 0.f;
  for (int p = 0; p < NPG; ++p)
    acc += gw[p] * xgn[(i64)(g * NPG + p) * CDIM + tid];
  pooled[(i64)g * CDIM + tid] = acc;
}

// conv2(1->10,k=9,pad=4) then mean over out-channels == 9-tap filter + bias
__global__ void fold_conv2(const float* __restrict__ w, const float* __restrict__ b,
                           float* __restrict__ wbar) {
  int tid = threadIdx.x;
  if (tid < 9) {
    float s = 0.f;
    for (int o = 0; o < 10; ++o) s += w[o * 9 + tid];
    wbar[tid] = s * 0.1f;
  } else if (tid == 9) {
    float s = 0.f;
    for (int o = 0; o < 10; ++o) s += b[o];
    wbar[9] = s * 0.1f;
  }
}

__global__ __launch_bounds__(256) void conv2mean(const float* __restrict__ pooled,
                                                 const float* __restrict__ wbar,
                                                 float* __restrict__ y2) {
  int b = blockIdx.x, h = threadIdx.x;
  __shared__ float row[CDIM];
  row[h] = pooled[(i64)b * CDIM + h];
  __syncthreads();
  float s = wbar[9];
#pragma unroll
  for (int t = 0; t < 9; ++t) {
    int hh = h + t - 4;
    if (hh >= 0 && hh < CDIM) s += row[hh] * wbar[t];
  }
  y2[(i64)b * CDIM + h] = s;
}

// BN2 (affine) + fc + log_softmax
__global__ __launch_bounds__(256) void final_fc(
    const float* __restrict__ y2, const float* __restrict__ acc,
    const float* __restrict__ g2, const float* __restrict__ b2,
    const float* __restrict__ fcw, const float* __restrict__ fcb,
    float* __restrict__ out) {
  int b = blockIdx.x, tid = threadIdx.x;
  __shared__ float yn[CDIM];
  __shared__ float logits[10];
  __shared__ float red[2];
  float mu = acc[tid] / 512.f;
  float var = acc[CDIM + tid] / 512.f - mu * mu;
  yn[tid] = (y2[(i64)b * CDIM + tid] - mu) * rsqrtf(var + EPSBN) * g2[tid] + b2[tid];
  __syncthreads();
  if (tid < 10) {
    float s = fcb[tid];
    for (int h = 0; h < CDIM; ++h) s += yn[h] * fcw[h * 10 + tid];
    logits[tid] = s;
  }
  __syncthreads();
  if (tid == 0) {
    float m = -1e30f;
    for (int o = 0; o < 10; ++o) m = fmaxf(m, logits[o]);
    float s = 0.f;
    for (int o = 0; o < 10; ++o) s += expf(logits[o] - m);
    red[0] = m;
    red[1] = logf(s);
  }
  __syncthreads();
  if (tid < 10) out[(i64)b * 10 + tid] = logits[tid] - red[0] - red[1];
}

// ---------------------------------------------------------------------------
extern "C" void kernel_launch(void* const* d_in, const int* in_sizes, int n_in,
                              void* d_out, int out_size, void* d_ws, size_t ws_size,
                              hipStream_t stream) {
  (void)in_sizes; (void)n_in; (void)out_size;
  const float* x        = (const float*)d_in[0];
  const float* conv1_w  = (const float*)d_in[4];
  const float* conv1_b  = (const float*)d_in[5];
  const float* bn1_g    = (const float*)d_in[6];
  const float* bn1_b    = (const float*)d_in[7];
  const float* ll1_w    = (const float*)d_in[8];
  const float* ll1_b    = (const float*)d_in[9];
  const float* tag_w    = (const float*)d_in[10];
  const float* tag_b    = (const float*)d_in[11];
  const float* gat_w    = (const float*)d_in[12];
  const float* gat_asrc = (const float*)d_in[13];
  const float* gat_adst = (const float*)d_in[14];
  const float* gat_b    = (const float*)d_in[15];
  const float* lw_ih[2] = {(const float*)d_in[16], (const float*)d_in[20]};
  const float* lw_hh[2] = {(const float*)d_in[17], (const float*)d_in[21]};
  const float* lb_ih[2] = {(const float*)d_in[18], (const float*)d_in[22]};
  const float* lb_hh[2] = {(const float*)d_in[19], (const float*)d_in[23]};
  const float* jk_w     = (const float*)d_in[24];
  const float* fff_w1   = (const float*)d_in[26];
  const float* fff_b1   = (const float*)d_in[27];
  const float* fff_w2   = (const float*)d_in[28];
  const float* fff_b2   = (const float*)d_in[29];
  const float* gate_w1  = (const float*)d_in[30];
  const float* gate_b1  = (const float*)d_in[31];
  const float* gate_w2  = (const float*)d_in[32];
  const float* gate_b2  = (const float*)d_in[33];
  const float* conv2_w  = (const float*)d_in[34];
  const float* conv2_b  = (const float*)d_in[35];
  const float* bn2_g    = (const float*)d_in[36];
  const float* bn2_b    = (const float*)d_in[37];
  const float* fc_w     = (const float*)d_in[38];
  const float* fc_b     = (const float*)d_in[39];
  float* out = (float*)d_out;

  // ---- workspace layout (fits adaptively into ws_size; min ~105 MB) ----
  float* ws = (float*)d_ws;
  i64 off = 0;
  auto alloc = [&](i64 n) { float* p = ws + off; off += (n + 15) & ~(i64)15; return p; };
  float* seq    = alloc((i64)5 * NNODES * CDIM);   // 15,073,280 (GAT outs / JK seq)
  float* att    = alloc(10 * NNODES);              // [dir*5+t][n]
  float* xg     = alloc((i64)NNODES * CDIM);
  float* hbuf   = alloc((i64)NNODES * HID);
  float* hres   = alloc((i64)NNODES * HID);
  float* stats  = alloc(1024);
  float* Wp     = alloc(FDIM * HID);
  float* bp     = alloc(64);
  float* bsum[2]; bsum[0] = alloc(ZCOLS); bsum[1] = alloc(ZCOLS);
  float* gatev  = alloc(CDIM);
  float* gateb0 = alloc(16);
  float* wbar   = alloc(16);
  float* pooled = alloc((i64)NGR * CDIM);
  float* y2     = alloc((i64)NGR * CDIM);
  float* Zs = ws + off;                            // shared overlay region
  i64 S = (i64)(ws_size / 4) - off;                // floats available in Zs
  if (S < 0) S = 0;

  // LSTM chunking: per 128-row tile need 128*(896*2 + 3584) = 688,128 floats
  int Tch = (int)(S / 688128); if (Tch < 1) Tch = 1; if (Tch > 92) Tch = 92;
  // stage-4 chunking: ff1 tile = 128*512 = 65,536 floats after s4+xgn (6,029,312)
  i64 Sff = S - 6029312;
  int Tf = (int)(Sff / 65536); if (Tf < 1) Tf = 1; if (Tf > 92) Tf = 92;

  // overlays (lifetimes disjoint):
  float* xconv = Zs;                       // [N,128]  stage 1
  float* feats = Zs + 1507328;             // [N,128]  stage 2
  float* gbuf  = Zs + 3014656;             // [N,256]  stage 2 (ends 6,029,312)
  float* hch = Zs;                         // [Tch*128, 896] LSTM h
  float* cch = hch + (i64)Tch * 114688;    // [Tch*128, 896] LSTM c
  float* zch = cch + (i64)Tch * 114688;    // [Tch*128, 3584] LSTM z
  float* s4  = Zs;                         // [N,256]  stage 4 (xg+ff)
  float* xgn = s4 + 3014656;               // [N,256]  stage 4 normed
  float* ff1 = xgn + 3014656;              // [Tf*128, 512] stage 4 chunk

  // ---- stage 1: PE + conv1 + BN1(fold) + ll1 ----
  conv1_kernel<<<NGR, 256, 0, stream>>>(x, conv1_w, conv1_b, xconv);
  fill0<<<1, 256, 0, stream>>>(stats, 256);
  col_stats<<<184, 256, 0, stream>>>(xconv, NNODES, FDIM, stats);
  fold_ll1<<<1, 256, 0, stream>>>(stats, bn1_g, bn1_b, ll1_w, ll1_b, Wp, bp);
  sgemm<0><<<dim3(92, 1), 256, 0, stream>>>(xconv, Wp, hbuf, NNODES, HID, FDIM,
                                            bp, nullptr, 0, 0);

  // ---- stage 2: 5x (TAGConv + BN + GAT) ----
  for (int i = 0; i < 5; ++i) {
    tagprop<<<NGR, 256, 0, stream>>>(hbuf, feats);
    sgemm<0><<<dim3(92, 1), 256, 0, stream>>>(feats, tag_w + (i64)i * FDIM * HID, hres,
                                              NNODES, HID, FDIM, tag_b + i * HID,
                                              hbuf, 0, 0);
    fill0<<<1, 256, 0, stream>>>(stats, 64);
    col_stats<<<184, 256, 0, stream>>>(hres, NNODES, HID, stats);
    bn_norm<<<1024, 256, 0, stream>>>(hres, hbuf, stats, NNODES, HID);
    sgemm<0><<<dim3(92, 2), 256, 0, stream>>>(hbuf, gat_w + (i64)i * HID * CDIM, gbuf,
                                              NNODES, CDIM, HID, nullptr, nullptr, 0, 0);
    gat_kernel<<<NGR, 256, 0, stream>>>(gbuf, gat_asrc + i * 256, gat_adst + i * 256,
                                        gat_b + i * 256, seq + (i64)i * NNODES * CDIM);
  }

  // ---- stage 3: bi-LSTM JumpingKnowledge (row-chunked over all 5 steps) ----
  add2<<<14, 256, 0, stream>>>(lb_ih[0], lb_hh[0], bsum[0], ZCOLS);
  add2<<<14, 256, 0, stream>>>(lb_ih[1], lb_hh[1], bsum[1], ZCOLS);
  for (int dir = 0; dir < 2; ++dir) {
    for (int t0 = 0; t0 < 92; t0 += Tch) {
      int tiles = (92 - t0 < Tch) ? (92 - t0) : Tch;
      int rows = tiles * 128;
      i64 r0 = (i64)t0 * 128;
      fill0<<<2048, 256, 0, stream>>>(hch, (i64)2 * Tch * 114688);  // h and c
      for (int t = 0; t < 5; ++t) {
        int ts = dir ? 4 - t : t;
        sgemm<1><<<dim3(tiles, 28), 256, 0, stream>>>(
            seq + (i64)ts * NNODES * CDIM + r0 * CDIM, lw_ih[dir], zch,
            rows, ZCOLS, CDIM, bsum[dir], nullptr, 0, 0);
        if (t > 0)
          sgemm<1><<<dim3(tiles, 28), 256, 0, stream>>>(
              hch, lw_hh[dir], zch, rows, ZCOLS, JKH, nullptr, nullptr, 0, 1);
        lstm_gates<<<(rows * JKH + 255) / 256, 256, 0, stream>>>(zch, cch, hch, rows);
        att_dot<<<rows, 256, 0, stream>>>(hch, jk_w + dir * JKH,
                                          att + (i64)(dir * 5 + ts) * NNODES + r0);
      }
    }
  }
  jk_combine<<<NNODES, 256, 0, stream>>>(att, seq, xg);

  // ---- stage 4: FinalFeedForward + residual BN (row-chunked ff1) ----
  for (int t0 = 0; t0 < 92; t0 += Tf) {
    int tiles = (92 - t0 < Tf) ? (92 - t0) : Tf;
    int rows = tiles * 128;
    i64 r0 = (i64)t0 * 128;
    sgemm<0><<<dim3(tiles, 4), 256, 0, stream>>>(xg + r0 * CDIM, fff_w1, ff1,
                                                 rows, 512, CDIM, fff_b1, nullptr, 1, 0);
    sgemm<0><<<dim3(tiles, 2), 256, 0, stream>>>(ff1, fff_w2, s4 + r0 * CDIM,
                                                 rows, CDIM, 512, fff_b2,
                                                 xg + r0 * CDIM, 0, 0);
  }
  fill0<<<1, 256, 0, stream>>>(stats, 512);
  col_stats<<<184, 256, 0, stream>>>(s4, NNODES, CDIM, stats);
  bn_norm<<<4096, 256, 0, stream>>>(s4, xgn, stats, NNODES, CDIM);

  // ---- stage 5: GlobalAttention pool + conv2/mean + BN2 + fc + log_softmax ----
  fold_gate<<<1, 256, 0, stream>>>(gate_w1, gate_b1, gate_w2, gate_b2, gatev, gateb0);
  pool_kernel<<<NGR, 256, 0, stream>>>(xgn, gatev, gateb0, pooled);
  fold_conv2<<<1, 64, 0, stream>>>(conv2_w, conv2_b, wbar);
  conv2mean<<<NGR, 256, 0, stream>>>(pooled, wbar, y2);
  fill0<<<1, 256, 0, stream>>>(stats, 512);
  col_stats<<<64, 256, 0, stream>>>(y2, NGR, CDIM, stats);
  final_fc<<<NGR, 256, 0, stream>>>(y2, stats, bn2_g, bn2_b, fc_w, fc_b, out);
}

// Round 3
// 2256.935 us; speedup vs baseline: 5.6770x; 5.6770x over previous
//
#include <hip/hip_runtime.h>
#include <math.h>

// Fixed problem geometry (complete digraph per 23-node graph)
#define NNODES 11776
#define NGR    512
#define NPG    23
#define FDIM   128
#define HID    32
#define CDIM   256
#define JKH    896
#define ZCOLS  3584      // 4*JKH
#define EPSBN  1e-5f

typedef long long i64;
typedef unsigned short ushort_t;
typedef __attribute__((ext_vector_type(8))) short bf16x8;
typedef __attribute__((ext_vector_type(4))) float f32x4;

__device__ __forceinline__ float sigmoidf_(float x) { return 1.f / (1.f + expf(-x)); }

__device__ __forceinline__ ushort_t f2bf(float x) {
  unsigned u = __float_as_uint(x);
  return (ushort_t)((u + 0x7fffu + ((u >> 16) & 1u)) >> 16);
}
__device__ __forceinline__ float bf2f(ushort_t b) {
  return __uint_as_float(((unsigned)b) << 16);
}

__device__ __forceinline__ void gload16(const ushort_t* g, ushort_t* l) {
  __builtin_amdgcn_global_load_lds(
      (const __attribute__((address_space(1))) void*)g,
      (__attribute__((address_space(3))) void*)l, 16, 0, 0);
}

// ---------------------------------------------------------------------------
// Stage 1: positional encoding + Conv1d(23->23, k=3, pad=1) over feature axis
// ---------------------------------------------------------------------------
__global__ __launch_bounds__(256) void conv1_kernel(
    const float* __restrict__ x, const float* __restrict__ w,
    const float* __restrict__ bias, float* __restrict__ out) {
  int b = blockIdx.x;
  __shared__ float in[NPG][FDIM];
  __shared__ float wsh[NPG * NPG * 3];
  int tid = threadIdx.x;
  const float c0 = -2.f * logf(10000.f) / 23.f;
  for (int idx = tid; idx < NPG * FDIM; idx += 256) {
    int p = idx >> 7, f = idx & 127;
    int j = p >> 1;
    float ang = (float)f * expf(c0 * (float)j);
    float pe = (p & 1) ? cosf(ang) : sinf(ang);
    in[p][f] = x[(i64)(b * NPG + p) * FDIM + f] + pe;
  }
  for (int idx = tid; idx < NPG * NPG * 3; idx += 256) wsh[idx] = w[idx];
  __syncthreads();
  for (int idx = tid; idx < NPG * FDIM; idx += 256) {
    int o = idx >> 7, f = idx & 127;
    float acc = bias[o];
    for (int i = 0; i < NPG; ++i) {
      const float* wr = &wsh[(o * NPG + i) * 3];
      float s = in[i][f] * wr[1];
      if (f > 0)   s += in[i][f - 1] * wr[0];
      if (f < 127) s += in[i][f + 1] * wr[2];
      acc += s;
    }
    out[(i64)(b * NPG + o) * FDIM + f] = acc;
  }
}

// ---------------------------------------------------------------------------
// Column statistics (acc pre-zeroed): acc[c]+=sum, acc[cols+c]+=sumsq
// ---------------------------------------------------------------------------
__global__ __launch_bounds__(256) void col_stats(
    const float* __restrict__ X, int rows, int cols, float* __restrict__ acc) {
  int rpt = 256 / cols;
  int c = threadIdx.x % cols;
  int rsub = threadIdx.x / cols;
  float s = 0.f, q = 0.f;
  for (int r0 = blockIdx.x * rpt; r0 < rows; r0 += gridDim.x * rpt) {
    int r = r0 + rsub;
    if (r < rows) {
      float v = X[(i64)r * cols + c];
      s += v; q += v * v;
    }
  }
  __shared__ float sh[256];
  sh[threadIdx.x] = s;
  __syncthreads();
  if (threadIdx.x < cols) {
    float t = 0.f;
    for (int g = 0; g < rpt; ++g) t += sh[g * cols + c];
    atomicAdd(&acc[c], t);
  }
  __syncthreads();
  sh[threadIdx.x] = q;
  __syncthreads();
  if (threadIdx.x < cols) {
    float t = 0.f;
    for (int g = 0; g < rpt; ++g) t += sh[g * cols + c];
    atomicAdd(&acc[cols + c], t);
  }
}

// BN (affine=False), training mode, biased variance
__global__ void bn_norm(const float* __restrict__ X, float* __restrict__ Y,
                        const float* __restrict__ acc, int rows, int cols) {
  i64 total = (i64)rows * cols;
  i64 idx = (i64)blockIdx.x * 256 + threadIdx.x;
  i64 stride = (i64)gridDim.x * 256;
  float invR = 1.f / (float)rows;
  for (; idx < total; idx += stride) {
    int c = (int)(idx % cols);
    float mu = acc[c] * invR;
    float var = acc[cols + c] * invR - mu * mu;
    Y[idx] = (X[idx] - mu) * rsqrtf(var + EPSBN);
  }
}

// Fold BN1(affine) into ll1
__global__ __launch_bounds__(256) void fold_ll1(
    const float* __restrict__ acc, const float* __restrict__ g,
    const float* __restrict__ be, const float* __restrict__ w,
    const float* __restrict__ lb, float* __restrict__ Wp, float* __restrict__ bp) {
  int tid = threadIdx.x;
  const float invR = 1.f / (float)NNODES;
  for (int idx = tid; idx < FDIM * HID; idx += 256) {
    int k = idx >> 5;
    float mu = acc[k] * invR;
    float var = acc[FDIM + k] * invR - mu * mu;
    float scale = g[k] * rsqrtf(var + EPSBN);
    Wp[idx] = scale * w[idx];
  }
  if (tid < HID) {
    float s = lb[tid];
    for (int k = 0; k < FDIM; ++k) {
      float mu = acc[k] * invR;
      float var = acc[FDIM + k] * invR - mu * mu;
      float scale = g[k] * rsqrtf(var + EPSBN);
      s += (be[k] - mu * scale) * w[k * HID + tid];
    }
    bp[tid] = s;
  }
}

// ---------------------------------------------------------------------------
// fp32 SGEMM (small stages only). BT=0: B is [K,N]. 128x128x16, 8x8 micro.
// ---------------------------------------------------------------------------
template <int BT>
__global__ __launch_bounds__(256) void sgemm(
    const float* __restrict__ A, const float* __restrict__ B, float* __restrict__ C,
    int M, int N, int K,
    const float* __restrict__ bias, const float* __restrict__ resid,
    int act, int accumulate) {
  __shared__ float As[16][128];
  __shared__ float Bs[16][128];
  int tid = threadIdx.x;
  int bm0 = blockIdx.x * 128;
  int bn0 = blockIdx.y * 128;
  int tx = tid & 15, ty = tid >> 4;
  float acc[8][8];
#pragma unroll
  for (int i = 0; i < 8; ++i)
#pragma unroll
    for (int j = 0; j < 8; ++j) acc[i][j] = 0.f;

  int ar = tid >> 2;
  int akc = (tid & 3) << 2;
  bool bfull = (bn0 + 127 < N);

  for (int k0 = 0; k0 < K; k0 += 16) {
    {
      const float* ap = A + (i64)(bm0 + ar) * K + k0 + akc;
      float4 a0 = *(const float4*)ap;
      float4 a1 = *(const float4*)(ap + (i64)64 * K);
      As[akc + 0][ar] = a0.x; As[akc + 1][ar] = a0.y;
      As[akc + 2][ar] = a0.z; As[akc + 3][ar] = a0.w;
      As[akc + 0][ar + 64] = a1.x; As[akc + 1][ar + 64] = a1.y;
      As[akc + 2][ar + 64] = a1.z; As[akc + 3][ar + 64] = a1.w;
    }
    if (BT) {
      int br = tid >> 1;
      int bkc = (tid & 1) << 3;
      const float* bp = B + (i64)(bn0 + br) * K + k0 + bkc;
      float4 b0 = *(const float4*)bp;
      float4 b1 = *(const float4*)(bp + 4);
      Bs[bkc + 0][br] = b0.x; Bs[bkc + 1][br] = b0.y;
      Bs[bkc + 2][br] = b0.z; Bs[bkc + 3][br] = b0.w;
      Bs[bkc + 4][br] = b1.x; Bs[bkc + 5][br] = b1.y;
      Bs[bkc + 6][br] = b1.z; Bs[bkc + 7][br] = b1.w;
    } else {
      int bk = tid >> 4;
      int bn = (tid & 15) << 3;
      const float* bp = B + (i64)(k0 + bk) * N + bn0 + bn;
      if (bfull) {
        *(float4*)&Bs[bk][bn] = *(const float4*)bp;
        *(float4*)&Bs[bk][bn + 4] = *(const float4*)(bp + 4);
      } else {
#pragma unroll
        for (int q = 0; q < 8; ++q)
          Bs[bk][bn + q] = (bn0 + bn + q < N) ? bp[q] : 0.f;
      }
    }
    __syncthreads();
#pragma unroll
    for (int kk = 0; kk < 16; ++kk) {
      float a[8], b[8];
      *(float4*)(a)     = *(const float4*)&As[kk][ty * 8];
      *(float4*)(a + 4) = *(const float4*)&As[kk][ty * 8 + 4];
      *(float4*)(b)     = *(const float4*)&Bs[kk][tx * 8];
      *(float4*)(b + 4) = *(const float4*)&Bs[kk][tx * 8 + 4];
#pragma unroll
      for (int i = 0; i < 8; ++i)
#pragma unroll
        for (int j = 0; j < 8; ++j)
          acc[i][j] = fmaf(a[i], b[j], acc[i][j]);
    }
    __syncthreads();
  }
#pragma unroll
  for (int i = 0; i < 8; ++i) {
    int m = bm0 + ty * 8 + i;
#pragma unroll
    for (int j = 0; j < 8; ++j) {
      int n = bn0 + tx * 8 + j;
      if (n < N) {
        i64 ci = (i64)m * N + n;
        float v = acc[i][j];
        if (accumulate) {
          C[ci] += v;
        } else {
          if (bias) v += bias[n];
          if (act == 1) v = v > 0.f ? v : expm1f(v);
          if (resid) v += resid[ci];
          C[ci] = v;
        }
      }
    }
  }
}

// ---------------------------------------------------------------------------
// TAGConv propagation (group-sum trick)
// ---------------------------------------------------------------------------
__global__ __launch_bounds__(256) void tagprop(const float* __restrict__ h,
                                               float* __restrict__ feats) {
  int b = blockIdx.x;
  __shared__ float hsh[NPG * HID];
  __shared__ float S[HID];
  int tid = threadIdx.x;
  const float* hp = h + (i64)b * NPG * HID;
  for (int idx = tid; idx < NPG * HID; idx += 256) hsh[idx] = hp[idx];
  __syncthreads();
  if (tid < HID) {
    float s = 0.f;
    for (int p = 0; p < NPG; ++p) s += hsh[p * HID + tid];
    S[tid] = s;
  }
  __syncthreads();
  float wn = 1.f / 22.f;
  for (int idx = tid; idx < NPG * HID; idx += 256) {
    int p = idx >> 5, c = idx & 31;
    float f0 = hsh[idx];
    float Sc = S[c];
    float f1 = (Sc - f0) * wn;
    float f2 = (Sc - f1) * wn;
    float f3 = (Sc - f2) * wn;
    float* row = feats + (i64)(b * NPG + p) * FDIM;
    row[c] = f0;
    row[HID + c] = f1;
    row[2 * HID + c] = f2;
    row[3 * HID + c] = f3;
  }
}

// ---------------------------------------------------------------------------
// GAT layer (8 heads x 32 dims), dense 23x23 attn per group; writes bf16 seq
// ---------------------------------------------------------------------------
__global__ __launch_bounds__(256) void gat_kernel(
    const float* __restrict__ g, const float* __restrict__ asrc,
    const float* __restrict__ adst, const float* __restrict__ gbias,
    ushort_t* __restrict__ outseq) {
  int b = blockIdx.x;
  __shared__ float gsh[NPG * CDIM];
  __shared__ float ssrc[NPG * 8], sdst[NPG * 8], sinv[NPG * 8];
  __shared__ float ealpha[NPG * NPG * 8];
  int tid = threadIdx.x;
  const i64 base = (i64)b * NPG * CDIM;
  for (int idx = tid; idx < NPG * CDIM; idx += 256) gsh[idx] = g[base + idx];
  __syncthreads();
  if (tid < NPG * 8) {
    int p = tid >> 3, hd = tid & 7;
    float s1 = 0.f, s2 = 0.f;
    const float* gp = &gsh[p * CDIM + hd * 32];
#pragma unroll
    for (int d = 0; d < 32; ++d) {
      s1 += gp[d] * asrc[hd * 32 + d];
      s2 += gp[d] * adst[hd * 32 + d];
    }
    ssrc[tid] = s1;
    sdst[tid] = s2;
  }
  __syncthreads();
  if (tid < NPG * 8) {
    int v = tid >> 3, hd = tid & 7;
    float sd = sdst[v * 8 + hd];
    float e[NPG];
    float m = -1e30f;
#pragma unroll
    for (int u = 0; u < NPG; ++u) {
      float xv = ssrc[u * 8 + hd] + sd;
      xv = xv > 0.f ? xv : 0.2f * xv;
      e[u] = xv;
      m = fmaxf(m, xv);
    }
    float s = 0.f;
#pragma unroll
    for (int u = 0; u < NPG; ++u) {
      float t = expf(e[u] - m);
      ealpha[(v * NPG + u) * 8 + hd] = t;
      s += t;
    }
    sinv[tid] = 1.f / s;
  }
  __syncthreads();
  {
    int hd = tid >> 5, d = tid & 31;
    for (int v = 0; v < NPG; ++v) {
      float acc = 0.f;
#pragma unroll
      for (int u = 0; u < NPG; ++u)
        acc += ealpha[(v * NPG + u) * 8 + hd] * gsh[u * CDIM + hd * 32 + d];
      outseq[base + (i64)v * CDIM + hd * 32 + d] =
          f2bf(acc * sinv[v * 8 + hd] + gbias[hd * 32 + d]);
    }
  }
}

// ---------------------------------------------------------------------------
// weight packing: row g*896+j -> packed row p=(j>>4)*64+g*16+(j&15), bf16
// ---------------------------------------------------------------------------
__global__ void pack_w(const float* __restrict__ w, ushort_t* __restrict__ wp,
                       int ldK) {
  i64 total = (i64)ZCOLS * ldK;
  i64 idx = (i64)blockIdx.x * 256 + threadIdx.x;
  i64 stride = (i64)gridDim.x * 256;
  for (; idx < total; idx += stride) {
    int r = (int)(idx / ldK), k = (int)(idx % ldK);
    int g = r / JKH, jj = r % JKH;
    int p = (jj >> 4) * 64 + g * 16 + (jj & 15);
    wp[(i64)p * ldK + k] = f2bf(w[idx]);
  }
}

__global__ void pack_b(const float* __restrict__ a, const float* __restrict__ b,
                       float* __restrict__ bp) {
  int r = blockIdx.x * 256 + threadIdx.x;
  if (r < ZCOLS) {
    int g = r / JKH, jj = r % JKH;
    int p = (jj >> 4) * 64 + g * 16 + (jj & 15);
    bp[p] = a[r] + b[r];
  }
}

// ---------------------------------------------------------------------------
// Fused LSTM step: z = seq@Wih^T [+ h@Whh^T] + b  -> gates -> c,h
// bf16 MFMA 16x16x32, 128x128 tile, gate-packed N layout.
// Wave (of 4): wm=(w&1)*64 rows, wn=(w>>1)*64 cols = one 16-j block x 4 gates.
// ---------------------------------------------------------------------------
template <int HASH>
__global__ __launch_bounds__(256) void lstm_step(
    const ushort_t* __restrict__ Aseq,   // [rows,256] bf16
    const ushort_t* __restrict__ Wih,    // [3584,256] bf16 packed
    const ushort_t* __restrict__ Hprev,  // [rows,896] bf16
    const ushort_t* __restrict__ Whh,    // [3584,896] bf16 packed
    const float*  __restrict__ bspk,     // [3584] packed bias
    float* __restrict__ Cst,             // [rows,896] fp32 (in-place)
    ushort_t* __restrict__ Hout) {       // [rows,896] bf16
  __shared__ ushort_t As[128 * 64];
  __shared__ ushort_t Bs[128 * 64];
  int tid = threadIdx.x;
  int w = tid >> 6, lane = tid & 63;
  int m0 = blockIdx.x * 128;
  int n0 = blockIdx.y * 128;
  f32x4 acc[4][4];
#pragma unroll
  for (int a = 0; a < 4; ++a)
#pragma unroll
    for (int b = 0; b < 4; ++b) acc[a][b] = (f32x4){0.f, 0.f, 0.f, 0.f};

  const ushort_t* aptr = Aseq;
  const ushort_t* bptr = Wih;
  int lda = CDIM, K = CDIM;
  for (int phase = 0; phase < (HASH ? 2 : 1); ++phase) {
    for (int k0 = 0; k0 < K; k0 += 64) {
      // stage A[m0..+127][k0..+63] and B[n0..+127][k0..+63] with chunk swizzle
#pragma unroll
      for (int i = 0; i < 4; ++i) {
        int r = w + i * 4;                // region 0..15
        int s = r * 64 + lane;            // 16B slot 0..1023
        int row = s >> 3;
        int kc = (s & 7) ^ (row & 7);
        gload16(aptr + (i64)(m0 + row) * lda + k0 + kc * 8, &As[r * 512]);
        gload16(bptr + (i64)(n0 + row) * lda + k0 + kc * 8, &Bs[r * 512]);
      }
      __syncthreads();
#pragma unroll
      for (int ks = 0; ks < 2; ++ks) {
        bf16x8 af[4], bfr[4];
        int kq = ks * 4 + (lane >> 4);
#pragma unroll
        for (int mi = 0; mi < 4; ++mi) {
          int row = (w & 1) * 64 + mi * 16 + (lane & 15);
          int pos = row * 8 + (kq ^ (row & 7));
          af[mi] = *(const bf16x8*)&As[pos * 8];
        }
#pragma unroll
        for (int ni = 0; ni < 4; ++ni) {
          int row = (w >> 1) * 64 + ni * 16 + (lane & 15);
          int pos = row * 8 + (kq ^ (row & 7));
          bfr[ni] = *(const bf16x8*)&Bs[pos * 8];
        }
#pragma unroll
        for (int mi = 0; mi < 4; ++mi)
#pragma unroll
          for (int ni = 0; ni < 4; ++ni)
            acc[mi][ni] = __builtin_amdgcn_mfma_f32_16x16x32_bf16(
                af[mi], bfr[ni], acc[mi][ni], 0, 0, 0);
      }
      __syncthreads();
    }
    aptr = Hprev; bptr = Whh; lda = JKH; K = JKH;
  }

  // epilogue: acc[mi][gate][reg]; j block = this wave's 64-col group
  int jb = (n0 >> 6) + (w >> 1);
  int j = jb * 16 + (lane & 15);
  float bsi = bspk[jb * 64 + (lane & 15)];
  float bsf = bspk[jb * 64 + 16 + (lane & 15)];
  float bsg = bspk[jb * 64 + 32 + (lane & 15)];
  float bso = bspk[jb * 64 + 48 + (lane & 15)];
#pragma unroll
  for (int mi = 0; mi < 4; ++mi) {
#pragma unroll
    for (int reg = 0; reg < 4; ++reg) {
      int m = m0 + (w & 1) * 64 + mi * 16 + (lane >> 4) * 4 + reg;
      float zi = acc[mi][0][reg] + bsi;
      float zf = acc[mi][1][reg] + bsf;
      float zg = acc[mi][2][reg] + bsg;
      float zo = acc[mi][3][reg] + bso;
      i64 ci = (i64)m * JKH + j;
      float cv = sigmoidf_(zi) * tanhf(zg);
      if (HASH) cv += sigmoidf_(zf) * Cst[ci];
      Cst[ci] = cv;
      Hout[ci] = f2bf(sigmoidf_(zo) * tanhf(cv));
    }
  }
}

// out[n] = dot(bf16 h[n,:], jkw[0:896])
__global__ __launch_bounds__(256) void att_dot(const ushort_t* __restrict__ H,
                                               const float* __restrict__ jkw,
                                               float* __restrict__ out) {
  int n = blockIdx.x;
  const ushort_t* h = H + (i64)n * JKH;
  float s = 0.f;
  for (int j = threadIdx.x; j < JKH; j += 256) s += bf2f(h[j]) * jkw[j];
  __shared__ float sh[4];
#pragma unroll
  for (int o = 32; o > 0; o >>= 1) s += __shfl_down(s, o, 64);
  if ((threadIdx.x & 63) == 0) sh[threadIdx.x >> 6] = s;
  __syncthreads();
  if (threadIdx.x == 0) out[n] = sh[0] + sh[1] + sh[2] + sh[3];
}

// softmax over the 5 layers, weighted sum of bf16 seq -> xg
__global__ __launch_bounds__(256) void jk_combine(const float* __restrict__ att,
                                                  const ushort_t* __restrict__ seq,
                                                  float* __restrict__ xg) {
  int n = blockIdx.x, c = threadIdx.x;
  float a[5];
  float m = -1e30f;
#pragma unroll
  for (int t = 0; t < 5; ++t) {
    a[t] = att[(i64)t * NNODES + n] + att[(i64)(5 + t) * NNODES + n];
    m = fmaxf(m, a[t]);
  }
  float s = 0.f;
#pragma unroll
  for (int t = 0; t < 5; ++t) { a[t] = expf(a[t] - m); s += a[t]; }
  float inv = 1.f / s;
  float acc = 0.f;
#pragma unroll
  for (int t = 0; t < 5; ++t)
    acc += bf2f(seq[((i64)t * NNODES + n) * CDIM + c]) * (a[t] * inv);
  xg[(i64)n * CDIM + c] = acc;
}

__global__ void fill0(float* __restrict__ p, i64 nfloat) {
  i64 i = (i64)blockIdx.x * 256 + threadIdx.x;
  i64 stride = (i64)gridDim.x * 256;
  for (; i < nfloat; i += stride) p[i] = 0.f;
}

// gate vector fold
__global__ __launch_bounds__(256) void fold_gate(
    const float* __restrict__ w1, const float* __restrict__ b1,
    const float* __restrict__ w2, const float* __restrict__ b2,
    float* __restrict__ v, float* __restrict__ b0) {
  int tid = threadIdx.x;
  float s = 0.f;
  for (int j = 0; j < 672; ++j) s += w1[tid * 672 + j] * w2[j];
  v[tid] = s;
  float p = 0.f;
  for (int j = tid; j < 672; j += 256) p += b1[j] * w2[j];
  __shared__ float sh[4];
#pragma unroll
  for (int o = 32; o > 0; o >>= 1) p += __shfl_down(p, o, 64);
  if ((tid & 63) == 0) sh[tid >> 6] = p;
  __syncthreads();
  if (tid == 0) b0[0] = sh[0] + sh[1] + sh[2] + sh[3] + b2[0];
}

// GlobalAttention pooling per graph
__global__ __launch_bounds__(256) void pool_kernel(
    const float* __restrict__ xgn, const float* __restrict__ v,
    const float* __restrict__ b0, float* __restrict__ pooled) {
  int g = blockIdx.x, tid = threadIdx.x;
  __shared__ float gw[NPG];
  __shared__ float sh[4];
  float myv = v[tid];
  for (int p = 0; p < NPG; ++p) {
    float val = xgn[(i64)(g * NPG + p) * CDIM + tid] * myv;
#pragma unroll
    for (int o = 32; o > 0; o >>= 1) val += __shfl_down(val, o, 64);
    if ((tid & 63) == 0) sh[tid >> 6] = val;
    __syncthreads();
    if (tid == 0) gw[p] = sh[0] + sh[1] + sh[2] + sh[3] + b0[0];
    __syncthreads();
  }
  if (tid == 0) {
    float m = -1e30f;
    for (int p = 0; p < NPG; ++p) m = fmaxf(m, gw[p]);
    float s = 0.f;
    for (int p = 0; p < NPG; ++p) { gw[p] = expf(gw[p] - m); s += gw[p]; }
    float inv = 1.f / s;
    for (int p = 0; p < NPG; ++p) gw[p] *= inv;
  }
  __syncthreads();
  float acc = 0.f;
  for (int p = 0; p < NPG; ++p)
    acc += gw[p] * xgn[(i64)(g * NPG + p) * CDIM + tid];
  pooled[(i64)g * CDIM + tid] = acc;
}

__global__ void fold_conv2(const float* __restrict__ w, const float* __restrict__ b,
                           float* __restrict__ wbar) {
  int tid = threadIdx.x;
  if (tid < 9) {
    float s = 0.f;
    for (int o = 0; o < 10; ++o) s += w[o * 9 + tid];
    wbar[tid] = s * 0.1f;
  } else if (tid == 9) {
    float s = 0.f;
    for (int o = 0; o < 10; ++o) s += b[o];
    wbar[9] = s * 0.1f;
  }
}

__global__ __launch_bounds__(256) void conv2mean(const float* __restrict__ pooled,
                                                 const float* __restrict__ wbar,
                                                 float* __restrict__ y2) {
  int b = blockIdx.x, h = threadIdx.x;
  __shared__ float row[CDIM];
  row[h] = pooled[(i64)b * CDIM + h];
  __syncthreads();
  float s = wbar[9];
#pragma unroll
  for (int t = 0; t < 9; ++t) {
    int hh = h + t - 4;
    if (hh >= 0 && hh < CDIM) s += row[hh] * wbar[t];
  }
  y2[(i64)b * CDIM + h] = s;
}

__global__ __launch_bounds__(256) void final_fc(
    const float* __restrict__ y2, const float* __restrict__ acc,
    const float* __restrict__ g2, const float* __restrict__ b2,
    const float* __restrict__ fcw, const float* __restrict__ fcb,
    float* __restrict__ out) {
  int b = blockIdx.x, tid = threadIdx.x;
  __shared__ float yn[CDIM];
  __shared__ float logits[10];
  __shared__ float red[2];
  float mu = acc[tid] / 512.f;
  float var = acc[CDIM + tid] / 512.f - mu * mu;
  yn[tid] = (y2[(i64)b * CDIM + tid] - mu) * rsqrtf(var + EPSBN) * g2[tid] + b2[tid];
  __syncthreads();
  if (tid < 10) {
    float s = fcb[tid];
    for (int h = 0; h < CDIM; ++h) s += yn[h] * fcw[h * 10 + tid];
    logits[tid] = s;
  }
  __syncthreads();
  if (tid == 0) {
    float m = -1e30f;
    for (int o = 0; o < 10; ++o) m = fmaxf(m, logits[o]);
    float s = 0.f;
    for (int o = 0; o < 10; ++o) s += expf(logits[o] - m);
    red[0] = m;
    red[1] = logf(s);
  }
  __syncthreads();
  if (tid < 10) out[(i64)b * 10 + tid] = logits[tid] - red[0] - red[1];
}

// ---------------------------------------------------------------------------
extern "C" void kernel_launch(void* const* d_in, const int* in_sizes, int n_in,
                              void* d_out, int out_size, void* d_ws, size_t ws_size,
                              hipStream_t stream) {
  (void)in_sizes; (void)n_in; (void)out_size;
  const float* x        = (const float*)d_in[0];
  const float* conv1_w  = (const float*)d_in[4];
  const float* conv1_b  = (const float*)d_in[5];
  const float* bn1_g    = (const float*)d_in[6];
  const float* bn1_b    = (const float*)d_in[7];
  const float* ll1_w    = (const float*)d_in[8];
  const float* ll1_b    = (const float*)d_in[9];
  const float* tag_w    = (const float*)d_in[10];
  const float* tag_b    = (const float*)d_in[11];
  const float* gat_w    = (const float*)d_in[12];
  const float* gat_asrc = (const float*)d_in[13];
  const float* gat_adst = (const float*)d_in[14];
  const float* gat_b    = (const float*)d_in[15];
  const float* lw_ih[2] = {(const float*)d_in[16], (const float*)d_in[20]};
  const float* lw_hh[2] = {(const float*)d_in[17], (const float*)d_in[21]};
  const float* lb_ih[2] = {(const float*)d_in[18], (const float*)d_in[22]};
  const float* lb_hh[2] = {(const float*)d_in[19], (const float*)d_in[23]};
  const float* jk_w     = (const float*)d_in[24];
  const float* fff_w1   = (const float*)d_in[26];
  const float* fff_b1   = (const float*)d_in[27];
  const float* fff_w2   = (const float*)d_in[28];
  const float* fff_b2   = (const float*)d_in[29];
  const float* gate_w1  = (const float*)d_in[30];
  const float* gate_b1  = (const float*)d_in[31];
  const float* gate_w2  = (const float*)d_in[32];
  const float* gate_b2  = (const float*)d_in[33];
  const float* conv2_w  = (const float*)d_in[34];
  const float* conv2_b  = (const float*)d_in[35];
  const float* bn2_g    = (const float*)d_in[36];
  const float* bn2_b    = (const float*)d_in[37];
  const float* fc_w     = (const float*)d_in[38];
  const float* fc_b     = (const float*)d_in[39];
  float* out = (float*)d_out;

  float* ws = (float*)d_ws;
  i64 off = 0;
  auto alloc = [&](i64 n) { float* p = ws + off; off += (n + 15) & ~(i64)15; return p; };
  // fixed allocations
  ushort_t* seqb = (ushort_t*)alloc(7536640);       // 5*N*256 bf16
  float* att    = alloc(10 * NNODES);
  float* xg     = alloc((i64)NNODES * CDIM);
  float* hbuf   = alloc((i64)NNODES * HID);
  float* hres   = alloc((i64)NNODES * HID);
  float* stats  = alloc(1024);
  float* Wp     = alloc(FDIM * HID);
  float* bp     = alloc(64);
  ushort_t* wihb[2]; ushort_t* whhb[2]; float* bspk[2];
  for (int d = 0; d < 2; ++d) {
    wihb[d] = (ushort_t*)alloc((i64)ZCOLS * CDIM / 2);   // bf16 [3584,256]
    whhb[d] = (ushort_t*)alloc((i64)ZCOLS * JKH / 2);    // bf16 [3584,896]
    bspk[d] = alloc(ZCOLS);
  }
  float* gatev  = alloc(CDIM);
  float* gateb0 = alloc(16);
  float* wbar   = alloc(16);
  float* pooled = alloc((i64)NGR * CDIM);
  float* y2     = alloc((i64)NGR * CDIM);
  float* Zs = ws + off;                              // shared overlay region
  i64 S = (i64)(ws_size / 4) - off;
  if (S < 0) S = 0;

  // LSTM chunk: per 128-row tile: hA 28672 + hB 28672 + c 114688 = 172032 floats
  int Tch = (int)(S / 172032); if (Tch < 1) Tch = 1; if (Tch > 92) Tch = 92;
  i64 Sff = S - 6029312;
  int Tf = (int)(Sff / 65536); if (Tf < 1) Tf = 1; if (Tf > 92) Tf = 92;

  // overlays (disjoint lifetimes)
  float* xconv = Zs;                        // [N,128] stage 1
  float* feats = Zs + 1507328;              // [N,128] stage 2
  float* gbuf  = Zs + 3014656;              // [N,256] stage 2
  ushort_t* hA = (ushort_t*)Zs;                       // [Tch*128,896] bf16
  ushort_t* hB = hA + (i64)Tch * 128 * JKH;           // [Tch*128,896] bf16
  float* cch   = (float*)(hB + (i64)Tch * 128 * JKH); // [Tch*128,896] fp32
  float* s4  = Zs;                          // [N,256] stage 4
  float* xgn = s4 + 3014656;                // [N,256]
  float* ff1 = xgn + 3014656;               // [Tf*128,512]

  // ---- weight packing (bf16, gate-interleaved) ----
  for (int d = 0; d < 2; ++d) {
    pack_w<<<2048, 256, 0, stream>>>(lw_ih[d], wihb[d], CDIM);
    pack_w<<<4096, 256, 0, stream>>>(lw_hh[d], whhb[d], JKH);
    pack_b<<<14, 256, 0, stream>>>(lb_ih[d], lb_hh[d], bspk[d]);
  }

  // ---- stage 1: PE + conv1 + BN1(fold) + ll1 ----
  conv1_kernel<<<NGR, 256, 0, stream>>>(x, conv1_w, conv1_b, xconv);
  fill0<<<1, 256, 0, stream>>>(stats, 256);
  col_stats<<<184, 256, 0, stream>>>(xconv, NNODES, FDIM, stats);
  fold_ll1<<<1, 256, 0, stream>>>(stats, bn1_g, bn1_b, ll1_w, ll1_b, Wp, bp);
  sgemm<0><<<dim3(92, 1), 256, 0, stream>>>(xconv, Wp, hbuf, NNODES, HID, FDIM,
                                            bp, nullptr, 0, 0);

  // ---- stage 2: 5x (TAGConv + BN + GAT) ----
  for (int i = 0; i < 5; ++i) {
    tagprop<<<NGR, 256, 0, stream>>>(hbuf, feats);
    sgemm<0><<<dim3(92, 1), 256, 0, stream>>>(feats, tag_w + (i64)i * FDIM * HID, hres,
                                              NNODES, HID, FDIM, tag_b + i * HID,
                                              hbuf, 0, 0);
    fill0<<<1, 256, 0, stream>>>(stats, 64);
    col_stats<<<184, 256, 0, stream>>>(hres, NNODES, HID, stats);
    bn_norm<<<1024, 256, 0, stream>>>(hres, hbuf, stats, NNODES, HID);
    sgemm<0><<<dim3(92, 2), 256, 0, stream>>>(hbuf, gat_w + (i64)i * HID * CDIM, gbuf,
                                              NNODES, CDIM, HID, nullptr, nullptr, 0, 0);
    gat_kernel<<<NGR, 256, 0, stream>>>(gbuf, gat_asrc + i * 256, gat_adst + i * 256,
                                        gat_b + i * 256, seqb + (i64)i * NNODES * CDIM);
  }

  // ---- stage 3: bi-LSTM, fused MFMA steps, row-chunked ----
  for (int dir = 0; dir < 2; ++dir) {
    for (int t0 = 0; t0 < 92; t0 += Tch) {
      int tiles = (92 - t0 < Tch) ? (92 - t0) : Tch;
      i64 r0 = (i64)t0 * 128;
      ushort_t* hp[2] = {hA, hB};
      for (int t = 0; t < 5; ++t) {
        int ts = dir ? 4 - t : t;
        const ushort_t* Ax = seqb + ((i64)ts * NNODES + r0) * CDIM;
        if (t == 0)
          lstm_step<0><<<dim3(tiles, 28), 256, 0, stream>>>(
              Ax, wihb[dir], nullptr, nullptr, bspk[dir], cch, hp[0]);
        else
          lstm_step<1><<<dim3(tiles, 28), 256, 0, stream>>>(
              Ax, wihb[dir], hp[(t + 1) & 1], whhb[dir], bspk[dir], cch, hp[t & 1]);
        att_dot<<<tiles * 128, 256, 0, stream>>>(
            hp[t & 1], jk_w + dir * JKH, att + (i64)(dir * 5 + ts) * NNODES + r0);
      }
    }
  }
  jk_combine<<<NNODES, 256, 0, stream>>>(att, seqb, xg);

  // ---- stage 4: FinalFeedForward + residual BN ----
  for (int t0 = 0; t0 < 92; t0 += Tf) {
    int tiles = (92 - t0 < Tf) ? (92 - t0) : Tf;
    int rows = tiles * 128;
    i64 r0 = (i64)t0 * 128;
    sgemm<0><<<dim3(tiles, 4), 256, 0, stream>>>(xg + r0 * CDIM, fff_w1, ff1,
                                                 rows, 512, CDIM, fff_b1, nullptr, 1, 0);
    sgemm<0><<<dim3(tiles, 2), 256, 0, stream>>>(ff1, fff_w2, s4 + r0 * CDIM,
                                                 rows, CDIM, 512, fff_b2,
                                                 xg + r0 * CDIM, 0, 0);
  }
  fill0<<<1, 256, 0, stream>>>(stats, 512);
  col_stats<<<184, 256, 0, stream>>>(s4, NNODES, CDIM, stats);
  bn_norm<<<4096, 256, 0, stream>>>(s4, xgn, stats, NNODES, CDIM);

  // ---- stage 5: pool + conv2/mean + BN2 + fc + log_softmax ----
  fold_gate<<<1, 256, 0, stream>>>(gate_w1, gate_b1, gate_w2, gate_b2, gatev, gateb0);
  pool_kernel<<<NGR, 256, 0, stream>>>(xgn, gatev, gateb0, pooled);
  fold_conv2<<<1, 64, 0, stream>>>(conv2_w, conv2_b, wbar);
  conv2mean<<<NGR, 256, 0, stream>>>(pooled, wbar, y2);
  fill0<<<1, 256, 0, stream>>>(stats, 512);
  col_stats<<<64, 256, 0, stream>>>(y2, NGR, CDIM, stats);
  final_fc<<<NGR, 256, 0, stream>>>(y2, stats, bn2_g, bn2_b, fc_w, fc_b, out);
}

// Round 4
// 1898.200 us; speedup vs baseline: 6.7498x; 1.1890x over previous
//
#include <hip/hip_runtime.h>
#include <math.h>

// Fixed problem geometry (complete digraph per 23-node graph)
#define NNODES 11776
#define NGR    512
#define NPG    23
#define FDIM   128
#define HID    32
#define CDIM   256
#define JKH    896
#define ZCOLS  3584      // 4*JKH
#define EPSBN  1e-5f

typedef long long i64;
typedef unsigned short ushort_t;
typedef __attribute__((ext_vector_type(8))) short bf16x8;
typedef __attribute__((ext_vector_type(4))) float f32x4;

__device__ __forceinline__ float sigmoidf_(float x) { return 1.f / (1.f + expf(-x)); }

__device__ __forceinline__ ushort_t f2bf(float x) {
  unsigned u = __float_as_uint(x);
  return (ushort_t)((u + 0x7fffu + ((u >> 16) & 1u)) >> 16);
}
__device__ __forceinline__ float bf2f(ushort_t b) {
  return __uint_as_float(((unsigned)b) << 16);
}

__device__ __forceinline__ void gload16(const ushort_t* g, ushort_t* l) {
  __builtin_amdgcn_global_load_lds(
      (const __attribute__((address_space(1))) void*)g,
      (__attribute__((address_space(3))) void*)l, 16, 0, 0);
}

// ---------------------------------------------------------------------------
// Stage 1: PE + Conv1d(23->23,k=3,pad=1) over feature axis + fused col-stats
// ---------------------------------------------------------------------------
__global__ __launch_bounds__(256) void conv1_kernel(
    const float* __restrict__ x, const float* __restrict__ w,
    const float* __restrict__ bias, float* __restrict__ out,
    float* __restrict__ stats) {
  int b = blockIdx.x;
  __shared__ float in[NPG][FDIM];
  __shared__ float wsh[NPG * NPG * 3];
  __shared__ float cs[FDIM], cq[FDIM];
  int tid = threadIdx.x;
  if (tid < FDIM) { cs[tid] = 0.f; cq[tid] = 0.f; }
  const float c0 = -2.f * logf(10000.f) / 23.f;
  for (int idx = tid; idx < NPG * FDIM; idx += 256) {
    int p = idx >> 7, f = idx & 127;
    int j = p >> 1;
    float ang = (float)f * expf(c0 * (float)j);
    float pe = (p & 1) ? cosf(ang) : sinf(ang);
    in[p][f] = x[(i64)(b * NPG + p) * FDIM + f] + pe;
  }
  for (int idx = tid; idx < NPG * NPG * 3; idx += 256) wsh[idx] = w[idx];
  __syncthreads();
  float ls = 0.f, lq = 0.f;
  int fme = tid & 127;
  for (int idx = tid; idx < NPG * FDIM; idx += 256) {
    int o = idx >> 7, f = idx & 127;
    float acc = bias[o];
    for (int i = 0; i < NPG; ++i) {
      const float* wr = &wsh[(o * NPG + i) * 3];
      float s = in[i][f] * wr[1];
      if (f > 0)   s += in[i][f - 1] * wr[0];
      if (f < 127) s += in[i][f + 1] * wr[2];
      acc += s;
    }
    out[(i64)(b * NPG + o) * FDIM + f] = acc;
    ls += acc; lq += acc * acc;
  }
  atomicAdd(&cs[fme], ls);
  atomicAdd(&cq[fme], lq);
  __syncthreads();
  if (tid < FDIM) {
    atomicAdd(&stats[tid], cs[tid]);
    atomicAdd(&stats[FDIM + tid], cq[tid]);
  }
}

// ---------------------------------------------------------------------------
// Column statistics (acc pre-zeroed) — stages 4/5 only
// ---------------------------------------------------------------------------
__global__ __launch_bounds__(256) void col_stats(
    const float* __restrict__ X, int rows, int cols, float* __restrict__ acc) {
  int rpt = 256 / cols;
  int c = threadIdx.x % cols;
  int rsub = threadIdx.x / cols;
  float s = 0.f, q = 0.f;
  for (int r0 = blockIdx.x * rpt; r0 < rows; r0 += gridDim.x * rpt) {
    int r = r0 + rsub;
    if (r < rows) {
      float v = X[(i64)r * cols + c];
      s += v; q += v * v;
    }
  }
  __shared__ float sh[256];
  sh[threadIdx.x] = s;
  __syncthreads();
  if (threadIdx.x < cols) {
    float t = 0.f;
    for (int g = 0; g < rpt; ++g) t += sh[g * cols + c];
    atomicAdd(&acc[c], t);
  }
  __syncthreads();
  sh[threadIdx.x] = q;
  __syncthreads();
  if (threadIdx.x < cols) {
    float t = 0.f;
    for (int g = 0; g < rpt; ++g) t += sh[g * cols + c];
    atomicAdd(&acc[cols + c], t);
  }
}

// BN (affine=False), training mode, biased variance
__global__ void bn_norm(const float* __restrict__ X, float* __restrict__ Y,
                        const float* __restrict__ acc, int rows, int cols) {
  i64 total = (i64)rows * cols;
  i64 idx = (i64)blockIdx.x * 256 + threadIdx.x;
  i64 stride = (i64)gridDim.x * 256;
  float invR = 1.f / (float)rows;
  for (; idx < total; idx += stride) {
    int c = (int)(idx % cols);
    float mu = acc[c] * invR;
    float var = acc[cols + c] * invR - mu * mu;
    Y[idx] = (X[idx] - mu) * rsqrtf(var + EPSBN);
  }
}

// Fold BN1(affine) into ll1
__global__ __launch_bounds__(256) void fold_ll1(
    const float* __restrict__ acc, const float* __restrict__ g,
    const float* __restrict__ be, const float* __restrict__ w,
    const float* __restrict__ lb, float* __restrict__ Wp, float* __restrict__ bp) {
  int tid = threadIdx.x;
  const float invR = 1.f / (float)NNODES;
  for (int idx = tid; idx < FDIM * HID; idx += 256) {
    int k = idx >> 5;
    float mu = acc[k] * invR;
    float var = acc[FDIM + k] * invR - mu * mu;
    float scale = g[k] * rsqrtf(var + EPSBN);
    Wp[idx] = scale * w[idx];
  }
  if (tid < HID) {
    float s = lb[tid];
    for (int k = 0; k < FDIM; ++k) {
      float mu = acc[k] * invR;
      float var = acc[FDIM + k] * invR - mu * mu;
      float scale = g[k] * rsqrtf(var + EPSBN);
      s += (be[k] - mu * scale) * w[k * HID + tid];
    }
    bp[tid] = s;
  }
}

// ---------------------------------------------------------------------------
// fp32 SGEMM (stages 1/4). BT=0: B is [K,N]. 128x128x16, 8x8 micro.
// ---------------------------------------------------------------------------
template <int BT>
__global__ __launch_bounds__(256) void sgemm(
    const float* __restrict__ A, const float* __restrict__ B, float* __restrict__ C,
    int M, int N, int K,
    const float* __restrict__ bias, const float* __restrict__ resid,
    int act, int accumulate) {
  __shared__ float As[16][128];
  __shared__ float Bs[16][128];
  int tid = threadIdx.x;
  int bm0 = blockIdx.x * 128;
  int bn0 = blockIdx.y * 128;
  int tx = tid & 15, ty = tid >> 4;
  float acc[8][8];
#pragma unroll
  for (int i = 0; i < 8; ++i)
#pragma unroll
    for (int j = 0; j < 8; ++j) acc[i][j] = 0.f;

  int ar = tid >> 2;
  int akc = (tid & 3) << 2;
  bool bfull = (bn0 + 127 < N);

  for (int k0 = 0; k0 < K; k0 += 16) {
    {
      const float* ap = A + (i64)(bm0 + ar) * K + k0 + akc;
      float4 a0 = *(const float4*)ap;
      float4 a1 = *(const float4*)(ap + (i64)64 * K);
      As[akc + 0][ar] = a0.x; As[akc + 1][ar] = a0.y;
      As[akc + 2][ar] = a0.z; As[akc + 3][ar] = a0.w;
      As[akc + 0][ar + 64] = a1.x; As[akc + 1][ar + 64] = a1.y;
      As[akc + 2][ar + 64] = a1.z; As[akc + 3][ar + 64] = a1.w;
    }
    if (BT) {
      int br = tid >> 1;
      int bkc = (tid & 1) << 3;
      const float* bp = B + (i64)(bn0 + br) * K + k0 + bkc;
      float4 b0 = *(const float4*)bp;
      float4 b1 = *(const float4*)(bp + 4);
      Bs[bkc + 0][br] = b0.x; Bs[bkc + 1][br] = b0.y;
      Bs[bkc + 2][br] = b0.z; Bs[bkc + 3][br] = b0.w;
      Bs[bkc + 4][br] = b1.x; Bs[bkc + 5][br] = b1.y;
      Bs[bkc + 6][br] = b1.z; Bs[bkc + 7][br] = b1.w;
    } else {
      int bk = tid >> 4;
      int bn = (tid & 15) << 3;
      const float* bp = B + (i64)(k0 + bk) * N + bn0 + bn;
      if (bfull) {
        *(float4*)&Bs[bk][bn] = *(const float4*)bp;
        *(float4*)&Bs[bk][bn + 4] = *(const float4*)(bp + 4);
      } else {
#pragma unroll
        for (int q = 0; q < 8; ++q)
          Bs[bk][bn + q] = (bn0 + bn + q < N) ? bp[q] : 0.f;
      }
    }
    __syncthreads();
#pragma unroll
    for (int kk = 0; kk < 16; ++kk) {
      float a[8], b[8];
      *(float4*)(a)     = *(const float4*)&As[kk][ty * 8];
      *(float4*)(a + 4) = *(const float4*)&As[kk][ty * 8 + 4];
      *(float4*)(b)     = *(const float4*)&Bs[kk][tx * 8];
      *(float4*)(b + 4) = *(const float4*)&Bs[kk][tx * 8 + 4];
#pragma unroll
      for (int i = 0; i < 8; ++i)
#pragma unroll
        for (int j = 0; j < 8; ++j)
          acc[i][j] = fmaf(a[i], b[j], acc[i][j]);
    }
    __syncthreads();
  }
#pragma unroll
  for (int i = 0; i < 8; ++i) {
    int m = bm0 + ty * 8 + i;
#pragma unroll
    for (int j = 0; j < 8; ++j) {
      int n = bn0 + tx * 8 + j;
      if (n < N) {
        i64 ci = (i64)m * N + n;
        float v = acc[i][j];
        if (accumulate) {
          C[ci] += v;
        } else {
          if (bias) v += bias[n];
          if (act == 1) v = v > 0.f ? v : expm1f(v);
          if (resid) v += resid[ci];
          C[ci] = v;
        }
      }
    }
  }
}

// ---------------------------------------------------------------------------
// Stage 2 kernel 1: TAGConv (feats in LDS) + tag GEMM + residual + BN stats
// one block per 23-node group
// ---------------------------------------------------------------------------
__global__ __launch_bounds__(256) void tag_fused(
    const float* __restrict__ hbuf, const float* __restrict__ tag_w,
    const float* __restrict__ tag_b, float* __restrict__ hres,
    float* __restrict__ stats) {
  int b = blockIdx.x, tid = threadIdx.x;
  __shared__ float fe[NPG][FDIM];
  __shared__ float wsh[FDIM * HID];
  __shared__ float S[HID];
  __shared__ float cs[HID], cq[HID];
  if (tid < HID) { cs[tid] = 0.f; cq[tid] = 0.f; }
  const float* hp = hbuf + (i64)b * NPG * HID;
  for (int idx = tid; idx < NPG * HID; idx += 256) fe[idx >> 5][idx & 31] = hp[idx];
  for (int idx = tid; idx < FDIM * HID; idx += 256) wsh[idx] = tag_w[idx];
  __syncthreads();
  if (tid < HID) {
    float s = 0.f;
    for (int p = 0; p < NPG; ++p) s += fe[p][tid];
    S[tid] = s;
  }
  __syncthreads();
  const float wn = 1.f / 22.f;
  for (int idx = tid; idx < NPG * HID; idx += 256) {
    int p = idx >> 5, c = idx & 31;
    float f0 = fe[p][c], Sc = S[c];
    float f1 = (Sc - f0) * wn;
    float f2 = (Sc - f1) * wn;
    float f3 = (Sc - f2) * wn;
    fe[p][HID + c] = f1;
    fe[p][2 * HID + c] = f2;
    fe[p][3 * HID + c] = f3;
  }
  __syncthreads();
  for (int idx = tid; idx < NPG * HID; idx += 256) {
    int p = idx >> 5, c = idx & 31;
    float acc = tag_b[c];
#pragma unroll 8
    for (int k = 0; k < FDIM; ++k) acc += fe[p][k] * wsh[k * HID + c];
    float v = fe[p][c] + acc;     // h + tag (residual)
    hres[(i64)(b * NPG + p) * HID + c] = v;
    atomicAdd(&cs[c], v);
    atomicAdd(&cq[c], v * v);
  }
  __syncthreads();
  if (tid < HID) {
    atomicAdd(&stats[tid], cs[tid]);
    atomicAdd(&stats[HID + tid], cq[tid]);
  }
}

// ---------------------------------------------------------------------------
// Stage 2 kernel 2: BN-normalize + GAT projection + dense 23x23 attention
// one block per group; writes normalized h (next layer) and bf16 seq
// ---------------------------------------------------------------------------
__global__ __launch_bounds__(256) void gat_fused(
    const float* __restrict__ hres, const float* __restrict__ stats,
    const float* __restrict__ gat_w, const float* __restrict__ asrc,
    const float* __restrict__ adst, const float* __restrict__ gbias,
    float* __restrict__ hout, ushort_t* __restrict__ outseq) {
  int b = blockIdx.x, tid = threadIdx.x;
  __shared__ float hn[NPG * HID];
  __shared__ float gsh[NPG * CDIM];
  __shared__ float ssrc[NPG * 8], sdst[NPG * 8], sinv[NPG * 8];
  __shared__ float ealpha[NPG * NPG * 8];
  const float invR = 1.f / (float)NNODES;
  for (int idx = tid; idx < NPG * HID; idx += 256) {
    int c = idx & 31;
    float mu = stats[c] * invR;
    float var = stats[HID + c] * invR - mu * mu;
    float v = (hres[(i64)b * NPG * HID + idx] - mu) * rsqrtf(var + EPSBN);
    hn[idx] = v;
    hout[(i64)b * NPG * HID + idx] = v;
  }
  __syncthreads();
  // g = hn @ gat_w  [23,256], gat_w [32,256] from global (L1/L2-resident)
  for (int idx = tid; idx < NPG * CDIM; idx += 256) {
    int p = idx >> 8, d = idx & 255;
    float acc = 0.f;
#pragma unroll
    for (int k = 0; k < HID; ++k) acc += hn[p * HID + k] * gat_w[k * CDIM + d];
    gsh[idx] = acc;
  }
  __syncthreads();
  if (tid < NPG * 8) {
    int p = tid >> 3, hd = tid & 7;
    float s1 = 0.f, s2 = 0.f;
    const float* gp = &gsh[p * CDIM + hd * 32];
#pragma unroll
    for (int d = 0; d < 32; ++d) {
      s1 += gp[d] * asrc[hd * 32 + d];
      s2 += gp[d] * adst[hd * 32 + d];
    }
    ssrc[tid] = s1;
    sdst[tid] = s2;
  }
  __syncthreads();
  if (tid < NPG * 8) {
    int v = tid >> 3, hd = tid & 7;
    float sd = sdst[v * 8 + hd];
    float e[NPG];
    float m = -1e30f;
#pragma unroll
    for (int u = 0; u < NPG; ++u) {
      float xv = ssrc[u * 8 + hd] + sd;
      xv = xv > 0.f ? xv : 0.2f * xv;
      e[u] = xv;
      m = fmaxf(m, xv);
    }
    float s = 0.f;
#pragma unroll
    for (int u = 0; u < NPG; ++u) {
      float t = expf(e[u] - m);
      ealpha[(v * NPG + u) * 8 + hd] = t;
      s += t;
    }
    sinv[tid] = 1.f / s;
  }
  __syncthreads();
  {
    int hd = tid >> 5, d = tid & 31;
    const i64 base = (i64)b * NPG * CDIM;
    for (int v = 0; v < NPG; ++v) {
      float acc = 0.f;
#pragma unroll
      for (int u = 0; u < NPG; ++u)
        acc += ealpha[(v * NPG + u) * 8 + hd] * gsh[u * CDIM + hd * 32 + d];
      outseq[base + (i64)v * CDIM + hd * 32 + d] =
          f2bf(acc * sinv[v * 8 + hd] + gbias[hd * 32 + d]);
    }
  }
}

// ---------------------------------------------------------------------------
// weight packing: row g*896+j -> packed row p=(j>>4)*64+g*16+(j&15), bf16
// ---------------------------------------------------------------------------
__global__ void pack_w(const float* __restrict__ w, ushort_t* __restrict__ wp,
                       int ldK) {
  i64 total = (i64)ZCOLS * ldK;
  i64 idx = (i64)blockIdx.x * 256 + threadIdx.x;
  i64 stride = (i64)gridDim.x * 256;
  for (; idx < total; idx += stride) {
    int r = (int)(idx / ldK), k = (int)(idx % ldK);
    int g = r / JKH, jj = r % JKH;
    int p = (jj >> 4) * 64 + g * 16 + (jj & 15);
    wp[(i64)p * ldK + k] = f2bf(w[idx]);
  }
}

__global__ void pack_b(const float* __restrict__ a, const float* __restrict__ b,
                       float* __restrict__ bp) {
  int r = blockIdx.x * 256 + threadIdx.x;
  if (r < ZCOLS) {
    int g = r / JKH, jj = r % JKH;
    int p = (jj >> 4) * 64 + g * 16 + (jj & 15);
    bp[p] = a[r] + b[r];
  }
}

// ---------------------------------------------------------------------------
// Fused LSTM step + JK attention dot: z = seq@Wih^T [+ h@Whh^T] + b -> gates
// -> c,h; att[m] += h[m,:] . jkw  (atomic, quad-shuffle-reduced)
// ---------------------------------------------------------------------------
template <int HASH>
__global__ __launch_bounds__(256) void lstm_step(
    const ushort_t* __restrict__ Aseq,   // [rows,256] bf16
    const ushort_t* __restrict__ Wih,    // [3584,256] bf16 packed
    const ushort_t* __restrict__ Hprev,  // [rows,896] bf16
    const ushort_t* __restrict__ Whh,    // [3584,896] bf16 packed
    const float*  __restrict__ bspk,     // [3584] packed bias
    float* __restrict__ Cst,             // [rows,896] fp32 (in-place)
    ushort_t* __restrict__ Hout,         // [rows,896] bf16
    const float* __restrict__ jkw,       // [896] this direction's jk weight
    float* __restrict__ attp) {          // [rows] atomic accum
  __shared__ ushort_t As[128 * 64];
  __shared__ ushort_t Bs[128 * 64];
  int tid = threadIdx.x;
  int w = tid >> 6, lane = tid & 63;
  int m0 = blockIdx.x * 128;
  int n0 = blockIdx.y * 128;
  f32x4 acc[4][4];
#pragma unroll
  for (int a = 0; a < 4; ++a)
#pragma unroll
    for (int b = 0; b < 4; ++b) acc[a][b] = (f32x4){0.f, 0.f, 0.f, 0.f};

  const ushort_t* aptr = Aseq;
  const ushort_t* bptr = Wih;
  int lda = CDIM, K = CDIM;
  for (int phase = 0; phase < (HASH ? 2 : 1); ++phase) {
    for (int k0 = 0; k0 < K; k0 += 64) {
#pragma unroll
      for (int i = 0; i < 4; ++i) {
        int r = w + i * 4;
        int s = r * 64 + lane;
        int row = s >> 3;
        int kc = (s & 7) ^ (row & 7);
        gload16(aptr + (i64)(m0 + row) * lda + k0 + kc * 8, &As[r * 512]);
        gload16(bptr + (i64)(n0 + row) * lda + k0 + kc * 8, &Bs[r * 512]);
      }
      __syncthreads();
#pragma unroll
      for (int ks = 0; ks < 2; ++ks) {
        bf16x8 af[4], bfr[4];
        int kq = ks * 4 + (lane >> 4);
#pragma unroll
        for (int mi = 0; mi < 4; ++mi) {
          int row = (w & 1) * 64 + mi * 16 + (lane & 15);
          int pos = row * 8 + (kq ^ (row & 7));
          af[mi] = *(const bf16x8*)&As[pos * 8];
        }
#pragma unroll
        for (int ni = 0; ni < 4; ++ni) {
          int row = (w >> 1) * 64 + ni * 16 + (lane & 15);
          int pos = row * 8 + (kq ^ (row & 7));
          bfr[ni] = *(const bf16x8*)&Bs[pos * 8];
        }
#pragma unroll
        for (int mi = 0; mi < 4; ++mi)
#pragma unroll
          for (int ni = 0; ni < 4; ++ni)
            acc[mi][ni] = __builtin_amdgcn_mfma_f32_16x16x32_bf16(
                af[mi], bfr[ni], acc[mi][ni], 0, 0, 0);
      }
      __syncthreads();
    }
    aptr = Hprev; bptr = Whh; lda = JKH; K = JKH;
  }

  // epilogue: acc[mi][gate][reg]; wave's 64-col group = one 16-j block x 4 gates
  int jb = (n0 >> 6) + (w >> 1);
  int j = jb * 16 + (lane & 15);
  float jw = jkw[j];
  float bsi = bspk[jb * 64 + (lane & 15)];
  float bsf = bspk[jb * 64 + 16 + (lane & 15)];
  float bsg = bspk[jb * 64 + 32 + (lane & 15)];
  float bso = bspk[jb * 64 + 48 + (lane & 15)];
#pragma unroll
  for (int mi = 0; mi < 4; ++mi) {
#pragma unroll
    for (int reg = 0; reg < 4; ++reg) {
      int m = m0 + (w & 1) * 64 + mi * 16 + (lane >> 4) * 4 + reg;
      float zi = acc[mi][0][reg] + bsi;
      float zf = acc[mi][1][reg] + bsf;
      float zg = acc[mi][2][reg] + bsg;
      float zo = acc[mi][3][reg] + bso;
      i64 ci = (i64)m * JKH + j;
      float cv = sigmoidf_(zi) * tanhf(zg);
      if (HASH) cv += sigmoidf_(zf) * Cst[ci];
      Cst[ci] = cv;
      float hv = sigmoidf_(zo) * tanhf(cv);
      Hout[ci] = f2bf(hv);
      // att partial: reduce over the 16 lanes of this quad (16 j's, same m)
      float av = hv * jw;
      av += __shfl_xor(av, 1, 64);
      av += __shfl_xor(av, 2, 64);
      av += __shfl_xor(av, 4, 64);
      av += __shfl_xor(av, 8, 64);
      if ((lane & 15) == 0) atomicAdd(&attp[m], av);
    }
  }
}

// softmax over the 5 layers, weighted sum of bf16 seq -> xg
__global__ __launch_bounds__(256) void jk_combine(const float* __restrict__ att,
                                                  const ushort_t* __restrict__ seq,
                                                  float* __restrict__ xg) {
  int n = blockIdx.x, c = threadIdx.x;
  float a[5];
  float m = -1e30f;
#pragma unroll
  for (int t = 0; t < 5; ++t) {
    a[t] = att[(i64)t * NNODES + n] + att[(i64)(5 + t) * NNODES + n];
    m = fmaxf(m, a[t]);
  }
  float s = 0.f;
#pragma unroll
  for (int t = 0; t < 5; ++t) { a[t] = expf(a[t] - m); s += a[t]; }
  float inv = 1.f / s;
  float acc = 0.f;
#pragma unroll
  for (int t = 0; t < 5; ++t)
    acc += bf2f(seq[((i64)t * NNODES + n) * CDIM + c]) * (a[t] * inv);
  xg[(i64)n * CDIM + c] = acc;
}

__global__ void fill0(float* __restrict__ p, i64 nfloat) {
  i64 i = (i64)blockIdx.x * 256 + threadIdx.x;
  i64 stride = (i64)gridDim.x * 256;
  for (; i < nfloat; i += stride) p[i] = 0.f;
}

// gate vector fold
__global__ __launch_bounds__(256) void fold_gate(
    const float* __restrict__ w1, const float* __restrict__ b1,
    const float* __restrict__ w2, const float* __restrict__ b2,
    float* __restrict__ v, float* __restrict__ b0) {
  int tid = threadIdx.x;
  float s = 0.f;
  for (int j = 0; j < 672; ++j) s += w1[tid * 672 + j] * w2[j];
  v[tid] = s;
  float p = 0.f;
  for (int j = tid; j < 672; j += 256) p += b1[j] * w2[j];
  __shared__ float sh[4];
#pragma unroll
  for (int o = 32; o > 0; o >>= 1) p += __shfl_down(p, o, 64);
  if ((tid & 63) == 0) sh[tid >> 6] = p;
  __syncthreads();
  if (tid == 0) b0[0] = sh[0] + sh[1] + sh[2] + sh[3] + b2[0];
}

// GlobalAttention pooling per graph
__global__ __launch_bounds__(256) void pool_kernel(
    const float* __restrict__ xgn, const float* __restrict__ v,
    const float* __restrict__ b0, float* __restrict__ pooled) {
  int g = blockIdx.x, tid = threadIdx.x;
  __shared__ float gw[NPG];
  __shared__ float sh[4];
  float myv = v[tid];
  for (int p = 0; p < NPG; ++p) {
    float val = xgn[(i64)(g * NPG + p) * CDIM + tid] * myv;
#pragma unroll
    for (int o = 32; o > 0; o >>= 1) val += __shfl_down(val, o, 64);
    if ((tid & 63) == 0) sh[tid >> 6] = val;
    __syncthreads();
    if (tid == 0) gw[p] = sh[0] + sh[1] + sh[2] + sh[3] + b0[0];
    __syncthreads();
  }
  if (tid == 0) {
    float m = -1e30f;
    for (int p = 0; p < NPG; ++p) m = fmaxf(m, gw[p]);
    float s = 0.f;
    for (int p = 0; p < NPG; ++p) { gw[p] = expf(gw[p] - m); s += gw[p]; }
    float inv = 1.f / s;
    for (int p = 0; p < NPG; ++p) gw[p] *= inv;
  }
  __syncthreads();
  float acc = 0.f;
  for (int p = 0; p < NPG; ++p)
    acc += gw[p] * xgn[(i64)(g * NPG + p) * CDIM + tid];
  pooled[(i64)g * CDIM + tid] = acc;
}

__global__ void fold_conv2(const float* __restrict__ w, const float* __restrict__ b,
                           float* __restrict__ wbar) {
  int tid = threadIdx.x;
  if (tid < 9) {
    float s = 0.f;
    for (int o = 0; o < 10; ++o) s += w[o * 9 + tid];
    wbar[tid] = s * 0.1f;
  } else if (tid == 9) {
    float s = 0.f;
    for (int o = 0; o < 10; ++o) s += b[o];
    wbar[9] = s * 0.1f;
  }
}

__global__ __launch_bounds__(256) void conv2mean(const float* __restrict__ pooled,
                                                 const float* __restrict__ wbar,
                                                 float* __restrict__ y2) {
  int b = blockIdx.x, h = threadIdx.x;
  __shared__ float row[CDIM];
  row[h] = pooled[(i64)b * CDIM + h];
  __syncthreads();
  float s = wbar[9];
#pragma unroll
  for (int t = 0; t < 9; ++t) {
    int hh = h + t - 4;
    if (hh >= 0 && hh < CDIM) s += row[hh] * wbar[t];
  }
  y2[(i64)b * CDIM + h] = s;
}

__global__ __launch_bounds__(256) void final_fc(
    const float* __restrict__ y2, const float* __restrict__ acc,
    const float* __restrict__ g2, const float* __restrict__ b2,
    const float* __restrict__ fcw, const float* __restrict__ fcb,
    float* __restrict__ out) {
  int b = blockIdx.x, tid = threadIdx.x;
  __shared__ float yn[CDIM];
  __shared__ float logits[10];
  __shared__ float red[2];
  float mu = acc[tid] / 512.f;
  float var = acc[CDIM + tid] / 512.f - mu * mu;
  yn[tid] = (y2[(i64)b * CDIM + tid] - mu) * rsqrtf(var + EPSBN) * g2[tid] + b2[tid];
  __syncthreads();
  if (tid < 10) {
    float s = fcb[tid];
    for (int h = 0; h < CDIM; ++h) s += yn[h] * fcw[h * 10 + tid];
    logits[tid] = s;
  }
  __syncthreads();
  if (tid == 0) {
    float m = -1e30f;
    for (int o = 0; o < 10; ++o) m = fmaxf(m, logits[o]);
    float s = 0.f;
    for (int o = 0; o < 10; ++o) s += expf(logits[o] - m);
    red[0] = m;
    red[1] = logf(s);
  }
  __syncthreads();
  if (tid < 10) out[(i64)b * 10 + tid] = logits[tid] - red[0] - red[1];
}

// ---------------------------------------------------------------------------
extern "C" void kernel_launch(void* const* d_in, const int* in_sizes, int n_in,
                              void* d_out, int out_size, void* d_ws, size_t ws_size,
                              hipStream_t stream) {
  (void)in_sizes; (void)n_in; (void)out_size;
  const float* x        = (const float*)d_in[0];
  const float* conv1_w  = (const float*)d_in[4];
  const float* conv1_b  = (const float*)d_in[5];
  const float* bn1_g    = (const float*)d_in[6];
  const float* bn1_b    = (const float*)d_in[7];
  const float* ll1_w    = (const float*)d_in[8];
  const float* ll1_b    = (const float*)d_in[9];
  const float* tag_w    = (const float*)d_in[10];
  const float* tag_b    = (const float*)d_in[11];
  const float* gat_w    = (const float*)d_in[12];
  const float* gat_asrc = (const float*)d_in[13];
  const float* gat_adst = (const float*)d_in[14];
  const float* gat_b    = (const float*)d_in[15];
  const float* lw_ih[2] = {(const float*)d_in[16], (const float*)d_in[20]};
  const float* lw_hh[2] = {(const float*)d_in[17], (const float*)d_in[21]};
  const float* lb_ih[2] = {(const float*)d_in[18], (const float*)d_in[22]};
  const float* lb_hh[2] = {(const float*)d_in[19], (const float*)d_in[23]};
  const float* jk_w     = (const float*)d_in[24];
  const float* fff_w1   = (const float*)d_in[26];
  const float* fff_b1   = (const float*)d_in[27];
  const float* fff_w2   = (const float*)d_in[28];
  const float* fff_b2   = (const float*)d_in[29];
  const float* gate_w1  = (const float*)d_in[30];
  const float* gate_b1  = (const float*)d_in[31];
  const float* gate_w2  = (const float*)d_in[32];
  const float* gate_b2  = (const float*)d_in[33];
  const float* conv2_w  = (const float*)d_in[34];
  const float* conv2_b  = (const float*)d_in[35];
  const float* bn2_g    = (const float*)d_in[36];
  const float* bn2_b    = (const float*)d_in[37];
  const float* fc_w     = (const float*)d_in[38];
  const float* fc_b     = (const float*)d_in[39];
  float* out = (float*)d_out;

  float* ws = (float*)d_ws;
  i64 off = 0;
  auto alloc = [&](i64 n) { float* p = ws + off; off += (n + 15) & ~(i64)15; return p; };
  // fixed allocations
  ushort_t* seqb = (ushort_t*)alloc(7536640);       // 5*N*256 bf16
  // zero-initialized region (one fill0): att + all stats buffers
  float* att = alloc(10 * NNODES);                  // 117760
  float* st1 = alloc(256);                          // conv1/bn1 stats
  float* st2 = alloc(5 * 64);                       // stage-2 per-layer stats
  float* st4 = alloc(512);                          // stage-4 stats
  float* st5 = alloc(512);                          // stage-5 stats
  i64 zcount = 117760 + 256 + 320 + 512 + 512 + 80; // covers padding
  float* xg     = alloc((i64)NNODES * CDIM);
  float* hbuf   = alloc((i64)NNODES * HID);
  float* hres   = alloc((i64)NNODES * HID);
  float* Wp     = alloc(FDIM * HID);
  float* bp     = alloc(64);
  ushort_t* wihb[2]; ushort_t* whhb[2]; float* bspk[2];
  for (int d = 0; d < 2; ++d) {
    wihb[d] = (ushort_t*)alloc((i64)ZCOLS * CDIM / 2);
    whhb[d] = (ushort_t*)alloc((i64)ZCOLS * JKH / 2);
    bspk[d] = alloc(ZCOLS);
  }
  float* gatev  = alloc(CDIM);
  float* gateb0 = alloc(16);
  float* wbar   = alloc(16);
  float* pooled = alloc((i64)NGR * CDIM);
  float* y2     = alloc((i64)NGR * CDIM);
  float* Zs = ws + off;                              // shared overlay region
  i64 S = (i64)(ws_size / 4) - off;
  if (S < 0) S = 0;

  // LSTM chunk: per 128-row tile: hA 28672 + hB 28672 + c 114688 = 172032 floats
  int Tch = (int)(S / 172032); if (Tch < 1) Tch = 1; if (Tch > 92) Tch = 92;
  i64 Sff = S - 6029312;
  int Tf = (int)(Sff / 65536); if (Tf < 1) Tf = 1; if (Tf > 92) Tf = 92;

  // overlays (disjoint lifetimes)
  float* xconv = Zs;                                  // [N,128] stage 1
  ushort_t* hA = (ushort_t*)Zs;                       // [Tch*128,896] bf16
  ushort_t* hB = hA + (i64)Tch * 128 * JKH;
  float* cch   = (float*)(hB + (i64)Tch * 128 * JKH); // [Tch*128,896] fp32
  float* s4  = Zs;                                    // [N,256] stage 4
  float* xgn = s4 + 3014656;                          // [N,256]
  float* ff1 = xgn + 3014656;                         // [Tf*128,512]

  // ---- zero att + stats in one shot; pack weights ----
  fill0<<<512, 256, 0, stream>>>(att, zcount);
  for (int d = 0; d < 2; ++d) {
    pack_w<<<2048, 256, 0, stream>>>(lw_ih[d], wihb[d], CDIM);
    pack_w<<<4096, 256, 0, stream>>>(lw_hh[d], whhb[d], JKH);
    pack_b<<<14, 256, 0, stream>>>(lb_ih[d], lb_hh[d], bspk[d]);
  }

  // ---- stage 1: PE + conv1 (+stats) + BN1-fold + ll1 ----
  conv1_kernel<<<NGR, 256, 0, stream>>>(x, conv1_w, conv1_b, xconv, st1);
  fold_ll1<<<1, 256, 0, stream>>>(st1, bn1_g, bn1_b, ll1_w, ll1_b, Wp, bp);
  sgemm<0><<<dim3(92, 1), 256, 0, stream>>>(xconv, Wp, hbuf, NNODES, HID, FDIM,
                                            bp, nullptr, 0, 0);

  // ---- stage 2: 5x (tag_fused + gat_fused) ----
  for (int i = 0; i < 5; ++i) {
    tag_fused<<<NGR, 256, 0, stream>>>(hbuf, tag_w + (i64)i * FDIM * HID,
                                       tag_b + i * HID, hres, st2 + i * 64);
    gat_fused<<<NGR, 256, 0, stream>>>(hres, st2 + i * 64,
                                       gat_w + (i64)i * HID * CDIM,
                                       gat_asrc + i * 256, gat_adst + i * 256,
                                       gat_b + i * 256, hbuf,
                                       seqb + (i64)i * NNODES * CDIM);
  }

  // ---- stage 3: bi-LSTM, fused MFMA steps + att dot, row-chunked ----
  for (int dir = 0; dir < 2; ++dir) {
    for (int t0 = 0; t0 < 92; t0 += Tch) {
      int tiles = (92 - t0 < Tch) ? (92 - t0) : Tch;
      i64 r0 = (i64)t0 * 128;
      ushort_t* hp[2] = {hA, hB};
      for (int t = 0; t < 5; ++t) {
        int ts = dir ? 4 - t : t;
        const ushort_t* Ax = seqb + ((i64)ts * NNODES + r0) * CDIM;
        float* attp = att + (i64)(dir * 5 + ts) * NNODES + r0;
        if (t == 0)
          lstm_step<0><<<dim3(tiles, 28), 256, 0, stream>>>(
              Ax, wihb[dir], nullptr, nullptr, bspk[dir], cch, hp[0],
              jk_w + dir * JKH, attp);
        else
          lstm_step<1><<<dim3(tiles, 28), 256, 0, stream>>>(
              Ax, wihb[dir], hp[(t + 1) & 1], whhb[dir], bspk[dir], cch, hp[t & 1],
              jk_w + dir * JKH, attp);
      }
    }
  }
  jk_combine<<<NNODES, 256, 0, stream>>>(att, seqb, xg);

  // ---- stage 4: FinalFeedForward + residual BN ----
  for (int t0 = 0; t0 < 92; t0 += Tf) {
    int tiles = (92 - t0 < Tf) ? (92 - t0) : Tf;
    int rows = tiles * 128;
    i64 r0 = (i64)t0 * 128;
    sgemm<0><<<dim3(tiles, 4), 256, 0, stream>>>(xg + r0 * CDIM, fff_w1, ff1,
                                                 rows, 512, CDIM, fff_b1, nullptr, 1, 0);
    sgemm<0><<<dim3(tiles, 2), 256, 0, stream>>>(ff1, fff_w2, s4 + r0 * CDIM,
                                                 rows, CDIM, 512, fff_b2,
                                                 xg + r0 * CDIM, 0, 0);
  }
  col_stats<<<184, 256, 0, stream>>>(s4, NNODES, CDIM, st4);
  bn_norm<<<4096, 256, 0, stream>>>(s4, xgn, st4, NNODES, CDIM);

  // ---- stage 5: pool + conv2/mean + BN2 + fc + log_softmax ----
  fold_gate<<<1, 256, 0, stream>>>(gate_w1, gate_b1, gate_w2, gate_b2, gatev, gateb0);
  pool_kernel<<<NGR, 256, 0, stream>>>(xgn, gatev, gateb0, pooled);
  fold_conv2<<<1, 64, 0, stream>>>(conv2_w, conv2_b, wbar);
  conv2mean<<<NGR, 256, 0, stream>>>(pooled, wbar, y2);
  col_stats<<<64, 256, 0, stream>>>(y2, NGR, CDIM, st5);
  final_fc<<<NGR, 256, 0, stream>>>(y2, st5, bn2_g, bn2_b, fc_w, fc_b, out);
}

// Round 5
// 1762.669 us; speedup vs baseline: 7.2688x; 1.0769x over previous
//
#include <hip/hip_runtime.h>
#include <math.h>

// Fixed problem geometry (complete digraph per 23-node graph)
#define NNODES 11776
#define NGR    512
#define NPG    23
#define FDIM   128
#define HID    32
#define CDIM   256
#define JKH    896
#define ZCOLS  3584      // 4*JKH
#define EPSBN  1e-5f

typedef long long i64;
typedef unsigned short ushort_t;
typedef __attribute__((ext_vector_type(8))) short bf16x8;
typedef __attribute__((ext_vector_type(4))) float f32x4;

__device__ __forceinline__ float sigmoidf_(float x) { return 1.f / (1.f + expf(-x)); }

__device__ __forceinline__ ushort_t f2bf(float x) {
  unsigned u = __float_as_uint(x);
  return (ushort_t)((u + 0x7fffu + ((u >> 16) & 1u)) >> 16);
}
__device__ __forceinline__ float bf2f(ushort_t b) {
  return __uint_as_float(((unsigned)b) << 16);
}

__device__ __forceinline__ void gload16(const ushort_t* g, ushort_t* l) {
  __builtin_amdgcn_global_load_lds(
      (const __attribute__((address_space(1))) void*)g,
      (__attribute__((address_space(3))) void*)l, 16, 0, 0);
}

// ---------------------------------------------------------------------------
// Stage 1: PE + Conv1d(23->23,k=3,pad=1) over feature axis + fused col-stats
// ---------------------------------------------------------------------------
__global__ __launch_bounds__(256) void conv1_kernel(
    const float* __restrict__ x, const float* __restrict__ w,
    const float* __restrict__ bias, float* __restrict__ out,
    float* __restrict__ stats) {
  int b = blockIdx.x;
  __shared__ float in[NPG][FDIM];
  __shared__ float wsh[NPG * NPG * 3];
  __shared__ float cs[FDIM], cq[FDIM];
  int tid = threadIdx.x;
  if (tid < FDIM) { cs[tid] = 0.f; cq[tid] = 0.f; }
  const float c0 = -2.f * logf(10000.f) / 23.f;
  for (int idx = tid; idx < NPG * FDIM; idx += 256) {
    int p = idx >> 7, f = idx & 127;
    int j = p >> 1;
    float ang = (float)f * expf(c0 * (float)j);
    float pe = (p & 1) ? cosf(ang) : sinf(ang);
    in[p][f] = x[(i64)(b * NPG + p) * FDIM + f] + pe;
  }
  for (int idx = tid; idx < NPG * NPG * 3; idx += 256) wsh[idx] = w[idx];
  __syncthreads();
  float ls = 0.f, lq = 0.f;
  int fme = tid & 127;
  for (int idx = tid; idx < NPG * FDIM; idx += 256) {
    int o = idx >> 7, f = idx & 127;
    float acc = bias[o];
    for (int i = 0; i < NPG; ++i) {
      const float* wr = &wsh[(o * NPG + i) * 3];
      float s = in[i][f] * wr[1];
      if (f > 0)   s += in[i][f - 1] * wr[0];
      if (f < 127) s += in[i][f + 1] * wr[2];
      acc += s;
    }
    out[(i64)(b * NPG + o) * FDIM + f] = acc;
    ls += acc; lq += acc * acc;
  }
  atomicAdd(&cs[fme], ls);
  atomicAdd(&cq[fme], lq);
  __syncthreads();
  if (tid < FDIM) {
    atomicAdd(&stats[tid], cs[tid]);
    atomicAdd(&stats[FDIM + tid], cq[tid]);
  }
}

// ---------------------------------------------------------------------------
// Column statistics (acc pre-zeroed) — stages 4/5
// ---------------------------------------------------------------------------
__global__ __launch_bounds__(256) void col_stats(
    const float* __restrict__ X, int rows, int cols, float* __restrict__ acc) {
  int rpt = 256 / cols;
  int c = threadIdx.x % cols;
  int rsub = threadIdx.x / cols;
  float s = 0.f, q = 0.f;
  for (int r0 = blockIdx.x * rpt; r0 < rows; r0 += gridDim.x * rpt) {
    int r = r0 + rsub;
    if (r < rows) {
      float v = X[(i64)r * cols + c];
      s += v; q += v * v;
    }
  }
  __shared__ float sh[256];
  sh[threadIdx.x] = s;
  __syncthreads();
  if (threadIdx.x < cols) {
    float t = 0.f;
    for (int g = 0; g < rpt; ++g) t += sh[g * cols + c];
    atomicAdd(&acc[c], t);
  }
  __syncthreads();
  sh[threadIdx.x] = q;
  __syncthreads();
  if (threadIdx.x < cols) {
    float t = 0.f;
    for (int g = 0; g < rpt; ++g) t += sh[g * cols + c];
    atomicAdd(&acc[cols + c], t);
  }
}

// BN (affine=False), training mode, biased variance
__global__ void bn_norm(const float* __restrict__ X, float* __restrict__ Y,
                        const float* __restrict__ acc, int rows, int cols) {
  i64 total = (i64)rows * cols;
  i64 idx = (i64)blockIdx.x * 256 + threadIdx.x;
  i64 stride = (i64)gridDim.x * 256;
  float invR = 1.f / (float)rows;
  for (; idx < total; idx += stride) {
    int c = (int)(idx % cols);
    float mu = acc[c] * invR;
    float var = acc[cols + c] * invR - mu * mu;
    Y[idx] = (X[idx] - mu) * rsqrtf(var + EPSBN);
  }
}

// Fold BN1(affine) into ll1
__global__ __launch_bounds__(256) void fold_ll1(
    const float* __restrict__ acc, const float* __restrict__ g,
    const float* __restrict__ be, const float* __restrict__ w,
    const float* __restrict__ lb, float* __restrict__ Wp, float* __restrict__ bp) {
  int tid = threadIdx.x;
  const float invR = 1.f / (float)NNODES;
  for (int idx = tid; idx < FDIM * HID; idx += 256) {
    int k = idx >> 5;
    float mu = acc[k] * invR;
    float var = acc[FDIM + k] * invR - mu * mu;
    float scale = g[k] * rsqrtf(var + EPSBN);
    Wp[idx] = scale * w[idx];
  }
  if (tid < HID) {
    float s = lb[tid];
    for (int k = 0; k < FDIM; ++k) {
      float mu = acc[k] * invR;
      float var = acc[FDIM + k] * invR - mu * mu;
      float scale = g[k] * rsqrtf(var + EPSBN);
      s += (be[k] - mu * scale) * w[k * HID + tid];
    }
    bp[tid] = s;
  }
}

// ---------------------------------------------------------------------------
// fp32 SGEMM (stage 1 only). BT=0: B is [K,N]. 128x128x16, 8x8 micro.
// ---------------------------------------------------------------------------
template <int BT>
__global__ __launch_bounds__(256) void sgemm(
    const float* __restrict__ A, const float* __restrict__ B, float* __restrict__ C,
    int M, int N, int K,
    const float* __restrict__ bias, const float* __restrict__ resid,
    int act, int accumulate) {
  __shared__ float As[16][128];
  __shared__ float Bs[16][128];
  int tid = threadIdx.x;
  int bm0 = blockIdx.x * 128;
  int bn0 = blockIdx.y * 128;
  int tx = tid & 15, ty = tid >> 4;
  float acc[8][8];
#pragma unroll
  for (int i = 0; i < 8; ++i)
#pragma unroll
    for (int j = 0; j < 8; ++j) acc[i][j] = 0.f;

  int ar = tid >> 2;
  int akc = (tid & 3) << 2;
  bool bfull = (bn0 + 127 < N);

  for (int k0 = 0; k0 < K; k0 += 16) {
    {
      const float* ap = A + (i64)(bm0 + ar) * K + k0 + akc;
      float4 a0 = *(const float4*)ap;
      float4 a1 = *(const float4*)(ap + (i64)64 * K);
      As[akc + 0][ar] = a0.x; As[akc + 1][ar] = a0.y;
      As[akc + 2][ar] = a0.z; As[akc + 3][ar] = a0.w;
      As[akc + 0][ar + 64] = a1.x; As[akc + 1][ar + 64] = a1.y;
      As[akc + 2][ar + 64] = a1.z; As[akc + 3][ar + 64] = a1.w;
    }
    if (BT) {
      int br = tid >> 1;
      int bkc = (tid & 1) << 3;
      const float* bp = B + (i64)(bn0 + br) * K + k0 + bkc;
      float4 b0 = *(const float4*)bp;
      float4 b1 = *(const float4*)(bp + 4);
      Bs[bkc + 0][br] = b0.x; Bs[bkc + 1][br] = b0.y;
      Bs[bkc + 2][br] = b0.z; Bs[bkc + 3][br] = b0.w;
      Bs[bkc + 4][br] = b1.x; Bs[bkc + 5][br] = b1.y;
      Bs[bkc + 6][br] = b1.z; Bs[bkc + 7][br] = b1.w;
    } else {
      int bk = tid >> 4;
      int bn = (tid & 15) << 3;
      const float* bp = B + (i64)(k0 + bk) * N + bn0 + bn;
      if (bfull) {
        *(float4*)&Bs[bk][bn] = *(const float4*)bp;
        *(float4*)&Bs[bk][bn + 4] = *(const float4*)(bp + 4);
      } else {
#pragma unroll
        for (int q = 0; q < 8; ++q)
          Bs[bk][bn + q] = (bn0 + bn + q < N) ? bp[q] : 0.f;
      }
    }
    __syncthreads();
#pragma unroll
    for (int kk = 0; kk < 16; ++kk) {
      float a[8], b[8];
      *(float4*)(a)     = *(const float4*)&As[kk][ty * 8];
      *(float4*)(a + 4) = *(const float4*)&As[kk][ty * 8 + 4];
      *(float4*)(b)     = *(const float4*)&Bs[kk][tx * 8];
      *(float4*)(b + 4) = *(const float4*)&Bs[kk][tx * 8 + 4];
#pragma unroll
      for (int i = 0; i < 8; ++i)
#pragma unroll
        for (int j = 0; j < 8; ++j)
          acc[i][j] = fmaf(a[i], b[j], acc[i][j]);
    }
    __syncthreads();
  }
#pragma unroll
  for (int i = 0; i < 8; ++i) {
    int m = bm0 + ty * 8 + i;
#pragma unroll
    for (int j = 0; j < 8; ++j) {
      int n = bn0 + tx * 8 + j;
      if (n < N) {
        i64 ci = (i64)m * N + n;
        float v = acc[i][j];
        if (accumulate) {
          C[ci] += v;
        } else {
          if (bias) v += bias[n];
          if (act == 1) v = v > 0.f ? v : expm1f(v);
          if (resid) v += resid[ci];
          C[ci] = v;
        }
      }
    }
  }
}

// ---------------------------------------------------------------------------
// Stage 2 opener: TAGConv layer 0 (feats in LDS) + residual + BN stats
// ---------------------------------------------------------------------------
__global__ __launch_bounds__(256) void tag_fused(
    const float* __restrict__ hbuf, const float* __restrict__ tag_w,
    const float* __restrict__ tag_b, float* __restrict__ hres,
    float* __restrict__ stats) {
  int b = blockIdx.x, tid = threadIdx.x;
  __shared__ float fe[NPG][FDIM];
  __shared__ float wsh[FDIM * HID];
  __shared__ float S[HID];
  __shared__ float cs[HID], cq[HID];
  if (tid < HID) { cs[tid] = 0.f; cq[tid] = 0.f; }
  const float* hp = hbuf + (i64)b * NPG * HID;
  for (int idx = tid; idx < NPG * HID; idx += 256) fe[idx >> 5][idx & 31] = hp[idx];
  for (int idx = tid; idx < FDIM * HID; idx += 256) wsh[idx] = tag_w[idx];
  __syncthreads();
  if (tid < HID) {
    float s = 0.f;
    for (int p = 0; p < NPG; ++p) s += fe[p][tid];
    S[tid] = s;
  }
  __syncthreads();
  const float wn = 1.f / 22.f;
  for (int idx = tid; idx < NPG * HID; idx += 256) {
    int p = idx >> 5, c = idx & 31;
    float f0 = fe[p][c], Sc = S[c];
    float f1 = (Sc - f0) * wn;
    float f2 = (Sc - f1) * wn;
    float f3 = (Sc - f2) * wn;
    fe[p][HID + c] = f1;
    fe[p][2 * HID + c] = f2;
    fe[p][3 * HID + c] = f3;
  }
  __syncthreads();
  for (int idx = tid; idx < NPG * HID; idx += 256) {
    int p = idx >> 5, c = idx & 31;
    float acc = tag_b[c];
#pragma unroll 8
    for (int k = 0; k < FDIM; ++k) acc += fe[p][k] * wsh[k * HID + c];
    float v = fe[p][c] + acc;
    hres[(i64)(b * NPG + p) * HID + c] = v;
    atomicAdd(&cs[c], v);
    atomicAdd(&cq[c], v * v);
  }
  __syncthreads();
  if (tid < HID) {
    atomicAdd(&stats[tid], cs[tid]);
    atomicAdd(&stats[HID + tid], cq[tid]);
  }
}

// ---------------------------------------------------------------------------
// Stage 2 main: BN-normalize + GAT (layer i) + TAGConv (layer i+1)
// one block per group; LDS union across the two phases
// ---------------------------------------------------------------------------
__global__ __launch_bounds__(256) void gat_tag_fused(
    const float* __restrict__ hres, const float* __restrict__ stats,
    const float* __restrict__ gat_w, const float* __restrict__ asrc,
    const float* __restrict__ adst, const float* __restrict__ gbias,
    ushort_t* __restrict__ outseq,
    const float* __restrict__ tag_w_next, const float* __restrict__ tag_b_next,
    float* __restrict__ hres_out, float* __restrict__ stats_next, int has_next) {
  int b = blockIdx.x, tid = threadIdx.x;
  __shared__ float hn[NPG * HID];
  __shared__ float ssrc[NPG * 8], sdst[NPG * 8], sinv[NPG * 8];
  __shared__ float buf[10120];   // A: gsh[5888]+ealpha[4232] | B: fe[2944]+wsh[4096]
  __shared__ float S[HID], cs[HID], cq[HID];
  float* gsh = buf;
  float* ealpha = buf + 5888;
  const float invR = 1.f / (float)NNODES;
  for (int idx = tid; idx < NPG * HID; idx += 256) {
    int c = idx & 31;
    float mu = stats[c] * invR;
    float var = stats[HID + c] * invR - mu * mu;
    hn[idx] = (hres[(i64)b * NPG * HID + idx] - mu) * rsqrtf(var + EPSBN);
  }
  __syncthreads();
  for (int idx = tid; idx < NPG * CDIM; idx += 256) {
    int p = idx >> 8, d = idx & 255;
    float acc = 0.f;
#pragma unroll
    for (int k = 0; k < HID; ++k) acc += hn[p * HID + k] * gat_w[k * CDIM + d];
    gsh[idx] = acc;
  }
  __syncthreads();
  if (tid < NPG * 8) {
    int p = tid >> 3, hd = tid & 7;
    float s1 = 0.f, s2 = 0.f;
    const float* gp = &gsh[p * CDIM + hd * 32];
#pragma unroll
    for (int d = 0; d < 32; ++d) {
      s1 += gp[d] * asrc[hd * 32 + d];
      s2 += gp[d] * adst[hd * 32 + d];
    }
    ssrc[tid] = s1;
    sdst[tid] = s2;
  }
  __syncthreads();
  if (tid < NPG * 8) {
    int v = tid >> 3, hd = tid & 7;
    float sd = sdst[v * 8 + hd];
    float e[NPG];
    float m = -1e30f;
#pragma unroll
    for (int u = 0; u < NPG; ++u) {
      float xv = ssrc[u * 8 + hd] + sd;
      xv = xv > 0.f ? xv : 0.2f * xv;
      e[u] = xv;
      m = fmaxf(m, xv);
    }
    float s = 0.f;
#pragma unroll
    for (int u = 0; u < NPG; ++u) {
      float t = expf(e[u] - m);
      ealpha[(v * NPG + u) * 8 + hd] = t;
      s += t;
    }
    sinv[tid] = 1.f / s;
  }
  __syncthreads();
  {
    int hd = tid >> 5, d = tid & 31;
    const i64 base = (i64)b * NPG * CDIM;
    for (int v = 0; v < NPG; ++v) {
      float acc = 0.f;
#pragma unroll
      for (int u = 0; u < NPG; ++u)
        acc += ealpha[(v * NPG + u) * 8 + hd] * gsh[u * CDIM + hd * 32 + d];
      outseq[base + (i64)v * CDIM + hd * 32 + d] =
          f2bf(acc * sinv[v * 8 + hd] + gbias[hd * 32 + d]);
    }
  }
  if (!has_next) return;
  __syncthreads();                 // done reading gsh/ealpha; reuse buf
  float* fe = buf;                 // [23][128]
  float* wsh = buf + 2944;         // [128*32]
  if (tid < HID) { cs[tid] = 0.f; cq[tid] = 0.f; }
  for (int idx = tid; idx < FDIM * HID; idx += 256) wsh[idx] = tag_w_next[idx];
  for (int idx = tid; idx < NPG * HID; idx += 256)
    fe[(idx >> 5) * FDIM + (idx & 31)] = hn[idx];
  __syncthreads();
  if (tid < HID) {
    float s = 0.f;
    for (int p = 0; p < NPG; ++p) s += fe[p * FDIM + tid];
    S[tid] = s;
  }
  __syncthreads();
  const float wn = 1.f / 22.f;
  for (int idx = tid; idx < NPG * HID; idx += 256) {
    int p = idx >> 5, c = idx & 31;
    float f0 = fe[p * FDIM + c], Sc = S[c];
    float f1 = (Sc - f0) * wn;
    float f2 = (Sc - f1) * wn;
    float f3 = (Sc - f2) * wn;
    fe[p * FDIM + HID + c] = f1;
    fe[p * FDIM + 2 * HID + c] = f2;
    fe[p * FDIM + 3 * HID + c] = f3;
  }
  __syncthreads();
  for (int idx = tid; idx < NPG * HID; idx += 256) {
    int p = idx >> 5, c = idx & 31;
    float acc = tag_b_next[c];
#pragma unroll 8
    for (int k = 0; k < FDIM; ++k) acc += fe[p * FDIM + k] * wsh[k * HID + c];
    float v = fe[p * FDIM + c] + acc;
    hres_out[(i64)(b * NPG + p) * HID + c] = v;
    atomicAdd(&cs[c], v);
    atomicAdd(&cq[c], v * v);
  }
  __syncthreads();
  if (tid < HID) {
    atomicAdd(&stats_next[tid], cs[tid]);
    atomicAdd(&stats_next[HID + tid], cq[tid]);
  }
}

// ---------------------------------------------------------------------------
// weight packing (LSTM): row g*896+j -> packed row p=(j>>4)*64+g*16+(j&15)
// ---------------------------------------------------------------------------
__global__ void pack_w(const float* __restrict__ w, ushort_t* __restrict__ wp,
                       int ldK) {
  i64 total = (i64)ZCOLS * ldK;
  i64 idx = (i64)blockIdx.x * 256 + threadIdx.x;
  i64 stride = (i64)gridDim.x * 256;
  for (; idx < total; idx += stride) {
    int r = (int)(idx / ldK), k = (int)(idx % ldK);
    int g = r / JKH, jj = r % JKH;
    int p = (jj >> 4) * 64 + g * 16 + (jj & 15);
    wp[(i64)p * ldK + k] = f2bf(w[idx]);
  }
}

__global__ void pack_b(const float* __restrict__ a, const float* __restrict__ b,
                       float* __restrict__ bp) {
  int r = blockIdx.x * 256 + threadIdx.x;
  if (r < ZCOLS) {
    int g = r / JKH, jj = r % JKH;
    int p = (jj >> 4) * 64 + g * 16 + (jj & 15);
    bp[p] = a[r] + b[r];
  }
}

// transpose-pack: w [K,N] fp32 -> wt [N,K] bf16
__global__ void pack_t(const float* __restrict__ w, ushort_t* __restrict__ wt,
                       int K, int N) {
  i64 total = (i64)K * N;
  i64 idx = (i64)blockIdx.x * 256 + threadIdx.x;
  i64 stride = (i64)gridDim.x * 256;
  for (; idx < total; idx += stride) {
    int k = (int)(idx / N), n = (int)(idx % N);
    wt[(i64)n * K + k] = f2bf(w[idx]);
  }
}

// ---------------------------------------------------------------------------
// Fused LSTM step + JK attention dot (LDS-pre-reduced)
// ---------------------------------------------------------------------------
template <int HASH>
__global__ __launch_bounds__(256) void lstm_step(
    const ushort_t* __restrict__ Aseq,   // [rows,256] bf16
    const ushort_t* __restrict__ Wih,    // [3584,256] bf16 packed
    const ushort_t* __restrict__ Hprev,  // [rows,896] bf16
    const ushort_t* __restrict__ Whh,    // [3584,896] bf16 packed
    const float*  __restrict__ bspk,     // [3584] packed bias
    float* __restrict__ Cst,             // [rows,896] fp32 (in-place)
    ushort_t* __restrict__ Hout,         // [rows,896] bf16
    const float* __restrict__ jkw,       // [896]
    float* __restrict__ attp) {          // [rows] atomic accum
  __shared__ ushort_t As[128 * 64];
  __shared__ ushort_t Bs[128 * 64];
  __shared__ float att_s[128];
  int tid = threadIdx.x;
  int w = tid >> 6, lane = tid & 63;
  int m0 = blockIdx.x * 128;
  int n0 = blockIdx.y * 128;
  f32x4 acc[4][4];
#pragma unroll
  for (int a = 0; a < 4; ++a)
#pragma unroll
    for (int b = 0; b < 4; ++b) acc[a][b] = (f32x4){0.f, 0.f, 0.f, 0.f};

  const ushort_t* aptr = Aseq;
  const ushort_t* bptr = Wih;
  int lda = CDIM, K = CDIM;
  for (int phase = 0; phase < (HASH ? 2 : 1); ++phase) {
    for (int k0 = 0; k0 < K; k0 += 64) {
#pragma unroll
      for (int i = 0; i < 4; ++i) {
        int r = w + i * 4;
        int s = r * 64 + lane;
        int row = s >> 3;
        int kc = (s & 7) ^ (row & 7);
        gload16(aptr + (i64)(m0 + row) * lda + k0 + kc * 8, &As[r * 512]);
        gload16(bptr + (i64)(n0 + row) * lda + k0 + kc * 8, &Bs[r * 512]);
      }
      __syncthreads();
#pragma unroll
      for (int ks = 0; ks < 2; ++ks) {
        bf16x8 af[4], bfr[4];
        int kq = ks * 4 + (lane >> 4);
#pragma unroll
        for (int mi = 0; mi < 4; ++mi) {
          int row = (w & 1) * 64 + mi * 16 + (lane & 15);
          int pos = row * 8 + (kq ^ (row & 7));
          af[mi] = *(const bf16x8*)&As[pos * 8];
        }
#pragma unroll
        for (int ni = 0; ni < 4; ++ni) {
          int row = (w >> 1) * 64 + ni * 16 + (lane & 15);
          int pos = row * 8 + (kq ^ (row & 7));
          bfr[ni] = *(const bf16x8*)&Bs[pos * 8];
        }
#pragma unroll
        for (int mi = 0; mi < 4; ++mi)
#pragma unroll
          for (int ni = 0; ni < 4; ++ni)
            acc[mi][ni] = __builtin_amdgcn_mfma_f32_16x16x32_bf16(
                af[mi], bfr[ni], acc[mi][ni], 0, 0, 0);
      }
      __syncthreads();
    }
    aptr = Hprev; bptr = Whh; lda = JKH; K = JKH;
  }

  if (tid < 128) att_s[tid] = 0.f;
  __syncthreads();

  int jb = (n0 >> 6) + (w >> 1);
  int j = jb * 16 + (lane & 15);
  float jw = jkw[j];
  float bsi = bspk[jb * 64 + (lane & 15)];
  float bsf = bspk[jb * 64 + 16 + (lane & 15)];
  float bsg = bspk[jb * 64 + 32 + (lane & 15)];
  float bso = bspk[jb * 64 + 48 + (lane & 15)];
#pragma unroll
  for (int mi = 0; mi < 4; ++mi) {
#pragma unroll
    for (int reg = 0; reg < 4; ++reg) {
      int mloc = (w & 1) * 64 + mi * 16 + (lane >> 4) * 4 + reg;
      int m = m0 + mloc;
      float zi = acc[mi][0][reg] + bsi;
      float zf = acc[mi][1][reg] + bsf;
      float zg = acc[mi][2][reg] + bsg;
      float zo = acc[mi][3][reg] + bso;
      i64 ci = (i64)m * JKH + j;
      float cv = sigmoidf_(zi) * tanhf(zg);
      if (HASH) cv += sigmoidf_(zf) * Cst[ci];
      Cst[ci] = cv;
      float hv = sigmoidf_(zo) * tanhf(cv);
      Hout[ci] = f2bf(hv);
      float av = hv * jw;
      av += __shfl_xor(av, 1, 64);
      av += __shfl_xor(av, 2, 64);
      av += __shfl_xor(av, 4, 64);
      av += __shfl_xor(av, 8, 64);
      if ((lane & 15) == 0) atomicAdd(&att_s[mloc], av);
    }
  }
  __syncthreads();
  if (tid < 128) atomicAdd(&attp[m0 + tid], att_s[tid]);
}

// ---------------------------------------------------------------------------
// bf16 MFMA GEMM (stage 4): C = [elu](A@Bt^T + bias) [+resid]
// A [M,K] bf16, Bt [N,K] bf16; plain N layout
// ---------------------------------------------------------------------------
template <int ACT, int BF16OUT>
__global__ __launch_bounds__(256) void mfma_gemm(
    const ushort_t* __restrict__ A, const ushort_t* __restrict__ Bt, int K,
    const float* __restrict__ bias, const float* __restrict__ resid,
    float* __restrict__ Cf, ushort_t* __restrict__ Cb, int N) {
  __shared__ ushort_t As[128 * 64];
  __shared__ ushort_t Bs[128 * 64];
  int tid = threadIdx.x;
  int w = tid >> 6, lane = tid & 63;
  int m0 = blockIdx.x * 128;
  int n0 = blockIdx.y * 128;
  f32x4 acc[4][4];
#pragma unroll
  for (int a = 0; a < 4; ++a)
#pragma unroll
    for (int b = 0; b < 4; ++b) acc[a][b] = (f32x4){0.f, 0.f, 0.f, 0.f};

  for (int k0 = 0; k0 < K; k0 += 64) {
#pragma unroll
    for (int i = 0; i < 4; ++i) {
      int r = w + i * 4;
      int s = r * 64 + lane;
      int row = s >> 3;
      int kc = (s & 7) ^ (row & 7);
      gload16(A + (i64)(m0 + row) * K + k0 + kc * 8, &As[r * 512]);
      gload16(Bt + (i64)(n0 + row) * K + k0 + kc * 8, &Bs[r * 512]);
    }
    __syncthreads();
#pragma unroll
    for (int ks = 0; ks < 2; ++ks) {
      bf16x8 af[4], bfr[4];
      int kq = ks * 4 + (lane >> 4);
#pragma unroll
      for (int mi = 0; mi < 4; ++mi) {
        int row = (w & 1) * 64 + mi * 16 + (lane & 15);
        int pos = row * 8 + (kq ^ (row & 7));
        af[mi] = *(const bf16x8*)&As[pos * 8];
      }
#pragma unroll
      for (int ni = 0; ni < 4; ++ni) {
        int row = (w >> 1) * 64 + ni * 16 + (lane & 15);
        int pos = row * 8 + (kq ^ (row & 7));
        bfr[ni] = *(const bf16x8*)&Bs[pos * 8];
      }
#pragma unroll
      for (int mi = 0; mi < 4; ++mi)
#pragma unroll
        for (int ni = 0; ni < 4; ++ni)
          acc[mi][ni] = __builtin_amdgcn_mfma_f32_16x16x32_bf16(
              af[mi], bfr[ni], acc[mi][ni], 0, 0, 0);
    }
    __syncthreads();
  }
#pragma unroll
  for (int ni = 0; ni < 4; ++ni) {
    int n = n0 + (w >> 1) * 64 + ni * 16 + (lane & 15);
    float bv = bias[n];
#pragma unroll
    for (int mi = 0; mi < 4; ++mi) {
#pragma unroll
      for (int reg = 0; reg < 4; ++reg) {
        int m = m0 + (w & 1) * 64 + mi * 16 + (lane >> 4) * 4 + reg;
        float v = acc[mi][ni][reg] + bv;
        if (ACT) v = v > 0.f ? v : expm1f(v);
        i64 ci = (i64)m * N + n;
        if (BF16OUT) Cb[ci] = f2bf(v);
        else Cf[ci] = v + resid[ci];
      }
    }
  }
}

// softmax over the 5 layers, weighted sum of bf16 seq -> xg (fp32 + bf16)
__global__ __launch_bounds__(256) void jk_combine(const float* __restrict__ att,
                                                  const ushort_t* __restrict__ seq,
                                                  float* __restrict__ xg,
                                                  ushort_t* __restrict__ xgb) {
  int n = blockIdx.x, c = threadIdx.x;
  float a[5];
  float m = -1e30f;
#pragma unroll
  for (int t = 0; t < 5; ++t) {
    a[t] = att[(i64)t * NNODES + n] + att[(i64)(5 + t) * NNODES + n];
    m = fmaxf(m, a[t]);
  }
  float s = 0.f;
#pragma unroll
  for (int t = 0; t < 5; ++t) { a[t] = expf(a[t] - m); s += a[t]; }
  float inv = 1.f / s;
  float acc = 0.f;
#pragma unroll
  for (int t = 0; t < 5; ++t)
    acc += bf2f(seq[((i64)t * NNODES + n) * CDIM + c]) * (a[t] * inv);
  xg[(i64)n * CDIM + c] = acc;
  xgb[(i64)n * CDIM + c] = f2bf(acc);
}

__global__ void fill0(float* __restrict__ p, i64 nfloat) {
  i64 i = (i64)blockIdx.x * 256 + threadIdx.x;
  i64 stride = (i64)gridDim.x * 256;
  for (; i < nfloat; i += stride) p[i] = 0.f;
}

// gate vector fold
__global__ __launch_bounds__(256) void fold_gate(
    const float* __restrict__ w1, const float* __restrict__ b1,
    const float* __restrict__ w2, const float* __restrict__ b2,
    float* __restrict__ v, float* __restrict__ b0) {
  int tid = threadIdx.x;
  float s = 0.f;
  for (int j = 0; j < 672; ++j) s += w1[tid * 672 + j] * w2[j];
  v[tid] = s;
  float p = 0.f;
  for (int j = tid; j < 672; j += 256) p += b1[j] * w2[j];
  __shared__ float sh[4];
#pragma unroll
  for (int o = 32; o > 0; o >>= 1) p += __shfl_down(p, o, 64);
  if ((tid & 63) == 0) sh[tid >> 6] = p;
  __syncthreads();
  if (tid == 0) b0[0] = sh[0] + sh[1] + sh[2] + sh[3] + b2[0];
}

// GlobalAttention pooling per graph
__global__ __launch_bounds__(256) void pool_kernel(
    const float* __restrict__ xgn, const float* __restrict__ v,
    const float* __restrict__ b0, float* __restrict__ pooled) {
  int g = blockIdx.x, tid = threadIdx.x;
  __shared__ float gw[NPG];
  __shared__ float sh[4];
  float myv = v[tid];
  for (int p = 0; p < NPG; ++p) {
    float val = xgn[(i64)(g * NPG + p) * CDIM + tid] * myv;
#pragma unroll
    for (int o = 32; o > 0; o >>= 1) val += __shfl_down(val, o, 64);
    if ((tid & 63) == 0) sh[tid >> 6] = val;
    __syncthreads();
    if (tid == 0) gw[p] = sh[0] + sh[1] + sh[2] + sh[3] + b0[0];
    __syncthreads();
  }
  if (tid == 0) {
    float m = -1e30f;
    for (int p = 0; p < NPG; ++p) m = fmaxf(m, gw[p]);
    float s = 0.f;
    for (int p = 0; p < NPG; ++p) { gw[p] = expf(gw[p] - m); s += gw[p]; }
    float inv = 1.f / s;
    for (int p = 0; p < NPG; ++p) gw[p] *= inv;
  }
  __syncthreads();
  float acc = 0.f;
  for (int p = 0; p < NPG; ++p)
    acc += gw[p] * xgn[(i64)(g * NPG + p) * CDIM + tid];
  pooled[(i64)g * CDIM + tid] = acc;
}

__global__ void fold_conv2(const float* __restrict__ w, const float* __restrict__ b,
                           float* __restrict__ wbar) {
  int tid = threadIdx.x;
  if (tid < 9) {
    float s = 0.f;
    for (int o = 0; o < 10; ++o) s += w[o * 9 + tid];
    wbar[tid] = s * 0.1f;
  } else if (tid == 9) {
    float s = 0.f;
    for (int o = 0; o < 10; ++o) s += b[o];
    wbar[9] = s * 0.1f;
  }
}

__global__ __launch_bounds__(256) void conv2mean(const float* __restrict__ pooled,
                                                 const float* __restrict__ wbar,
                                                 float* __restrict__ y2) {
  int b = blockIdx.x, h = threadIdx.x;
  __shared__ float row[CDIM];
  row[h] = pooled[(i64)b * CDIM + h];
  __syncthreads();
  float s = wbar[9];
#pragma unroll
  for (int t = 0; t < 9; ++t) {
    int hh = h + t - 4;
    if (hh >= 0 && hh < CDIM) s += row[hh] * wbar[t];
  }
  y2[(i64)b * CDIM + h] = s;
}

__global__ __launch_bounds__(256) void final_fc(
    const float* __restrict__ y2, const float* __restrict__ acc,
    const float* __restrict__ g2, const float* __restrict__ b2,
    const float* __restrict__ fcw, const float* __restrict__ fcb,
    float* __restrict__ out) {
  int b = blockIdx.x, tid = threadIdx.x;
  __shared__ float yn[CDIM];
  __shared__ float logits[10];
  __shared__ float red[2];
  float mu = acc[tid] / 512.f;
  float var = acc[CDIM + tid] / 512.f - mu * mu;
  yn[tid] = (y2[(i64)b * CDIM + tid] - mu) * rsqrtf(var + EPSBN) * g2[tid] + b2[tid];
  __syncthreads();
  if (tid < 10) {
    float s = fcb[tid];
    for (int h = 0; h < CDIM; ++h) s += yn[h] * fcw[h * 10 + tid];
    logits[tid] = s;
  }
  __syncthreads();
  if (tid == 0) {
    float m = -1e30f;
    for (int o = 0; o < 10; ++o) m = fmaxf(m, logits[o]);
    float s = 0.f;
    for (int o = 0; o < 10; ++o) s += expf(logits[o] - m);
    red[0] = m;
    red[1] = logf(s);
  }
  __syncthreads();
  if (tid < 10) out[(i64)b * 10 + tid] = logits[tid] - red[0] - red[1];
}

// ---------------------------------------------------------------------------
extern "C" void kernel_launch(void* const* d_in, const int* in_sizes, int n_in,
                              void* d_out, int out_size, void* d_ws, size_t ws_size,
                              hipStream_t stream) {
  (void)in_sizes; (void)n_in; (void)out_size;
  const float* x        = (const float*)d_in[0];
  const float* conv1_w  = (const float*)d_in[4];
  const float* conv1_b  = (const float*)d_in[5];
  const float* bn1_g    = (const float*)d_in[6];
  const float* bn1_b    = (const float*)d_in[7];
  const float* ll1_w    = (const float*)d_in[8];
  const float* ll1_b    = (const float*)d_in[9];
  const float* tag_w    = (const float*)d_in[10];
  const float* tag_b    = (const float*)d_in[11];
  const float* gat_w    = (const float*)d_in[12];
  const float* gat_asrc = (const float*)d_in[13];
  const float* gat_adst = (const float*)d_in[14];
  const float* gat_b    = (const float*)d_in[15];
  const float* lw_ih[2] = {(const float*)d_in[16], (const float*)d_in[20]};
  const float* lw_hh[2] = {(const float*)d_in[17], (const float*)d_in[21]};
  const float* lb_ih[2] = {(const float*)d_in[18], (const float*)d_in[22]};
  const float* lb_hh[2] = {(const float*)d_in[19], (const float*)d_in[23]};
  const float* jk_w     = (const float*)d_in[24];
  const float* fff_w1   = (const float*)d_in[26];
  const float* fff_b1   = (const float*)d_in[27];
  const float* fff_w2   = (const float*)d_in[28];
  const float* fff_b2   = (const float*)d_in[29];
  const float* gate_w1  = (const float*)d_in[30];
  const float* gate_b1  = (const float*)d_in[31];
  const float* gate_w2  = (const float*)d_in[32];
  const float* gate_b2  = (const float*)d_in[33];
  const float* conv2_w  = (const float*)d_in[34];
  const float* conv2_b  = (const float*)d_in[35];
  const float* bn2_g    = (const float*)d_in[36];
  const float* bn2_b    = (const float*)d_in[37];
  const float* fc_w     = (const float*)d_in[38];
  const float* fc_b     = (const float*)d_in[39];
  float* out = (float*)d_out;

  float* ws = (float*)d_ws;
  i64 off = 0;
  auto alloc = [&](i64 n) { float* p = ws + off; off += (n + 15) & ~(i64)15; return p; };
  ushort_t* seqb = (ushort_t*)alloc(7536640);       // 5*N*256 bf16
  // zero-initialized region (one fill0): att + all stats buffers
  float* att = alloc(10 * NNODES);
  float* st1 = alloc(256);
  float* st2 = alloc(6 * 64);
  float* st4 = alloc(512);
  float* st5 = alloc(512);
  i64 zcount = (i64)(st5 - att) + 512;
  float* xg     = alloc((i64)NNODES * CDIM);
  ushort_t* xgb = (ushort_t*)alloc((i64)NNODES * CDIM / 2);
  float* hbuf   = alloc((i64)NNODES * HID);
  float* hres   = alloc((i64)NNODES * HID);
  float* Wp     = alloc(FDIM * HID);
  float* bp     = alloc(64);
  ushort_t* wihb[2]; ushort_t* whhb[2]; float* bspk[2];
  for (int d = 0; d < 2; ++d) {
    wihb[d] = (ushort_t*)alloc((i64)ZCOLS * CDIM / 2);
    whhb[d] = (ushort_t*)alloc((i64)ZCOLS * JKH / 2);
    bspk[d] = alloc(ZCOLS);
  }
  ushort_t* w1t = (ushort_t*)alloc(512 * 256 / 2);  // [512,256] bf16
  ushort_t* w2t = (ushort_t*)alloc(256 * 512 / 2);  // [256,512] bf16
  float* gatev  = alloc(CDIM);
  float* gateb0 = alloc(16);
  float* wbar   = alloc(16);
  float* pooled = alloc((i64)NGR * CDIM);
  float* y2     = alloc((i64)NGR * CDIM);
  float* Zs = ws + off;                              // shared overlay region
  i64 S = (i64)(ws_size / 4) - off;
  if (S < 0) S = 0;

  // LSTM chunk: per 128-row tile: hA 28672 + hB 28672 + c 114688 = 172032 floats
  int Tch = (int)(S / 172032); if (Tch < 1) Tch = 1; if (Tch > 92) Tch = 92;
  // stage-4: s4+xgn = 6,029,312 floats; ff1b tile = 128*512 bf16 = 32768 floats
  i64 Sff = S - 6029312;
  int Tf = (int)(Sff / 32768); if (Tf < 1) Tf = 1; if (Tf > 92) Tf = 92;

  // overlays (disjoint lifetimes)
  float* xconv = Zs;                                  // [N,128] stage 1
  ushort_t* hA = (ushort_t*)Zs;                       // [Tch*128,896] bf16
  ushort_t* hB = hA + (i64)Tch * 128 * JKH;
  float* cch   = (float*)(hB + (i64)Tch * 128 * JKH); // [Tch*128,896] fp32
  float* s4  = Zs;                                    // [N,256] stage 4
  float* xgn = s4 + 3014656;                          // [N,256]
  ushort_t* ff1b = (ushort_t*)(xgn + 3014656);        // [Tf*128,512] bf16

  // ---- zero att+stats; pack weights ----
  fill0<<<512, 256, 0, stream>>>(att, zcount);
  for (int d = 0; d < 2; ++d) {
    pack_w<<<2048, 256, 0, stream>>>(lw_ih[d], wihb[d], CDIM);
    pack_w<<<4096, 256, 0, stream>>>(lw_hh[d], whhb[d], JKH);
    pack_b<<<14, 256, 0, stream>>>(lb_ih[d], lb_hh[d], bspk[d]);
  }
  pack_t<<<512, 256, 0, stream>>>(fff_w1, w1t, CDIM, 512);
  pack_t<<<512, 256, 0, stream>>>(fff_w2, w2t, 512, CDIM);

  // ---- stage 1: PE + conv1 (+stats) + BN1-fold + ll1 ----
  conv1_kernel<<<NGR, 256, 0, stream>>>(x, conv1_w, conv1_b, xconv, st1);
  fold_ll1<<<1, 256, 0, stream>>>(st1, bn1_g, bn1_b, ll1_w, ll1_b, Wp, bp);
  sgemm<0><<<dim3(92, 1), 256, 0, stream>>>(xconv, Wp, hbuf, NNODES, HID, FDIM,
                                            bp, nullptr, 0, 0);

  // ---- stage 2: tag layer0, then 5x fused GAT(i)+TAG(i+1) ----
  tag_fused<<<NGR, 256, 0, stream>>>(hbuf, tag_w, tag_b, hres, st2);
  for (int i = 0; i < 5; ++i) {
    int nx = (i < 4) ? (i + 1) : 0;   // dummy ptrs when has_next=0
    gat_tag_fused<<<NGR, 256, 0, stream>>>(
        hres, st2 + i * 64, gat_w + (i64)i * HID * CDIM,
        gat_asrc + i * 256, gat_adst + i * 256, gat_b + i * 256,
        seqb + (i64)i * NNODES * CDIM,
        tag_w + (i64)nx * FDIM * HID, tag_b + nx * HID,
        hres, st2 + (i + 1) * 64, (i < 4) ? 1 : 0);
  }

  // ---- stage 3: bi-LSTM, fused MFMA steps + att dot, row-chunked ----
  for (int dir = 0; dir < 2; ++dir) {
    for (int t0 = 0; t0 < 92; t0 += Tch) {
      int tiles = (92 - t0 < Tch) ? (92 - t0) : Tch;
      i64 r0 = (i64)t0 * 128;
      ushort_t* hp[2] = {hA, hB};
      for (int t = 0; t < 5; ++t) {
        int ts = dir ? 4 - t : t;
        const ushort_t* Ax = seqb + ((i64)ts * NNODES + r0) * CDIM;
        float* attp = att + (i64)(dir * 5 + ts) * NNODES + r0;
        if (t == 0)
          lstm_step<0><<<dim3(tiles, 28), 256, 0, stream>>>(
              Ax, wihb[dir], nullptr, nullptr, bspk[dir], cch, hp[0],
              jk_w + dir * JKH, attp);
        else
          lstm_step<1><<<dim3(tiles, 28), 256, 0, stream>>>(
              Ax, wihb[dir], hp[(t + 1) & 1], whhb[dir], bspk[dir], cch, hp[t & 1],
              jk_w + dir * JKH, attp);
      }
    }
  }
  jk_combine<<<NNODES, 256, 0, stream>>>(att, seqb, xg, xgb);

  // ---- stage 4: FFF (bf16 MFMA) + residual BN ----
  for (int t0 = 0; t0 < 92; t0 += Tf) {
    int tiles = (92 - t0 < Tf) ? (92 - t0) : Tf;
    i64 r0 = (i64)t0 * 128;
    mfma_gemm<1, 1><<<dim3(tiles, 4), 256, 0, stream>>>(
        xgb + r0 * CDIM, w1t, CDIM, fff_b1, nullptr, nullptr, ff1b, 512);
    mfma_gemm<0, 0><<<dim3(tiles, 2), 256, 0, stream>>>(
        ff1b, w2t, 512, fff_b2, xg + r0 * CDIM, s4 + r0 * CDIM, nullptr, CDIM);
  }
  col_stats<<<184, 256, 0, stream>>>(s4, NNODES, CDIM, st4);
  bn_norm<<<4096, 256, 0, stream>>>(s4, xgn, st4, NNODES, CDIM);

  // ---- stage 5: pool + conv2/mean + BN2 + fc + log_softmax ----
  fold_gate<<<1, 256, 0, stream>>>(gate_w1, gate_b1, gate_w2, gate_b2, gatev, gateb0);
  pool_kernel<<<NGR, 256, 0, stream>>>(xgn, gatev, gateb0, pooled);
  fold_conv2<<<1, 64, 0, stream>>>(conv2_w, conv2_b, wbar);
  conv2mean<<<NGR, 256, 0, stream>>>(pooled, wbar, y2);
  col_stats<<<64, 256, 0, stream>>>(y2, NGR, CDIM, st5);
  final_fc<<<NGR, 256, 0, stream>>>(y2, st5, bn2_g, bn2_b, fc_w, fc_b, out);
}

// Round 6
// 1674.150 us; speedup vs baseline: 7.6531x; 1.0529x over previous
//
#include <hip/hip_runtime.h>
#include <math.h>

// Fixed problem geometry (complete digraph per 23-node graph)
#define NNODES 11776
#define NGR    512
#define NPG    23
#define FDIM   128
#define HID    32
#define CDIM   256
#define JKH    896
#define ZCOLS  3584      // 4*JKH
#define EPSBN  1e-5f

typedef long long i64;
typedef unsigned short ushort_t;
typedef __attribute__((ext_vector_type(8))) short bf16x8;
typedef __attribute__((ext_vector_type(4))) float f32x4;

// fast transcendentals: v_exp_f32-based (error ~1e-7, invisible under bf16)
__device__ __forceinline__ float fsig(float x) { return 1.f / (1.f + __expf(-x)); }
__device__ __forceinline__ float ftanh(float x) {
  x = fminf(fmaxf(x, -15.f), 15.f);
  float e = __expf(2.f * x);
  return (e - 1.f) / (e + 1.f);
}

__device__ __forceinline__ ushort_t f2bf(float x) {
  unsigned u = __float_as_uint(x);
  return (ushort_t)((u + 0x7fffu + ((u >> 16) & 1u)) >> 16);
}
__device__ __forceinline__ float bf2f(ushort_t b) {
  return __uint_as_float(((unsigned)b) << 16);
}

__device__ __forceinline__ void gload16(const ushort_t* g, ushort_t* l) {
  __builtin_amdgcn_global_load_lds(
      (const __attribute__((address_space(1))) void*)g,
      (__attribute__((address_space(3))) void*)l, 16, 0, 0);
}

// ---------------------------------------------------------------------------
// Stage 1: PE + Conv1d(23->23,k=3,pad=1) over feature axis + fused col-stats
// ---------------------------------------------------------------------------
__global__ __launch_bounds__(256) void conv1_kernel(
    const float* __restrict__ x, const float* __restrict__ w,
    const float* __restrict__ bias, float* __restrict__ out,
    float* __restrict__ stats) {
  int b = blockIdx.x;
  __shared__ float in[NPG][FDIM];
  __shared__ float wsh[NPG * NPG * 3];
  __shared__ float cs[FDIM], cq[FDIM];
  int tid = threadIdx.x;
  if (tid < FDIM) { cs[tid] = 0.f; cq[tid] = 0.f; }
  const float c0 = -2.f * logf(10000.f) / 23.f;
  for (int idx = tid; idx < NPG * FDIM; idx += 256) {
    int p = idx >> 7, f = idx & 127;
    int j = p >> 1;
    float ang = (float)f * expf(c0 * (float)j);
    float pe = (p & 1) ? cosf(ang) : sinf(ang);
    in[p][f] = x[(i64)(b * NPG + p) * FDIM + f] + pe;
  }
  for (int idx = tid; idx < NPG * NPG * 3; idx += 256) wsh[idx] = w[idx];
  __syncthreads();
  float ls = 0.f, lq = 0.f;
  int fme = tid & 127;
  for (int idx = tid; idx < NPG * FDIM; idx += 256) {
    int o = idx >> 7, f = idx & 127;
    float acc = bias[o];
    for (int i = 0; i < NPG; ++i) {
      const float* wr = &wsh[(o * NPG + i) * 3];
      float s = in[i][f] * wr[1];
      if (f > 0)   s += in[i][f - 1] * wr[0];
      if (f < 127) s += in[i][f + 1] * wr[2];
      acc += s;
    }
    out[(i64)(b * NPG + o) * FDIM + f] = acc;
    ls += acc; lq += acc * acc;
  }
  atomicAdd(&cs[fme], ls);
  atomicAdd(&cq[fme], lq);
  __syncthreads();
  if (tid < FDIM) {
    atomicAdd(&stats[tid], cs[tid]);
    atomicAdd(&stats[FDIM + tid], cq[tid]);
  }
}

// ---------------------------------------------------------------------------
// Column statistics (acc pre-zeroed) — stage 5 only
// ---------------------------------------------------------------------------
__global__ __launch_bounds__(256) void col_stats(
    const float* __restrict__ X, int rows, int cols, float* __restrict__ acc) {
  int rpt = 256 / cols;
  int c = threadIdx.x % cols;
  int rsub = threadIdx.x / cols;
  float s = 0.f, q = 0.f;
  for (int r0 = blockIdx.x * rpt; r0 < rows; r0 += gridDim.x * rpt) {
    int r = r0 + rsub;
    if (r < rows) {
      float v = X[(i64)r * cols + c];
      s += v; q += v * v;
    }
  }
  __shared__ float sh[256];
  sh[threadIdx.x] = s;
  __syncthreads();
  if (threadIdx.x < cols) {
    float t = 0.f;
    for (int g = 0; g < rpt; ++g) t += sh[g * cols + c];
    atomicAdd(&acc[c], t);
  }
  __syncthreads();
  sh[threadIdx.x] = q;
  __syncthreads();
  if (threadIdx.x < cols) {
    float t = 0.f;
    for (int g = 0; g < rpt; ++g) t += sh[g * cols + c];
    atomicAdd(&acc[cols + c], t);
  }
}

// Fold BN1(affine) into ll1
__global__ __launch_bounds__(256) void fold_ll1(
    const float* __restrict__ acc, const float* __restrict__ g,
    const float* __restrict__ be, const float* __restrict__ w,
    const float* __restrict__ lb, float* __restrict__ Wp, float* __restrict__ bp) {
  int tid = threadIdx.x;
  const float invR = 1.f / (float)NNODES;
  for (int idx = tid; idx < FDIM * HID; idx += 256) {
    int k = idx >> 5;
    float mu = acc[k] * invR;
    float var = acc[FDIM + k] * invR - mu * mu;
    float scale = g[k] * rsqrtf(var + EPSBN);
    Wp[idx] = scale * w[idx];
  }
  if (tid < HID) {
    float s = lb[tid];
    for (int k = 0; k < FDIM; ++k) {
      float mu = acc[k] * invR;
      float var = acc[FDIM + k] * invR - mu * mu;
      float scale = g[k] * rsqrtf(var + EPSBN);
      s += (be[k] - mu * scale) * w[k * HID + tid];
    }
    bp[tid] = s;
  }
}

// ---------------------------------------------------------------------------
// fp32 SGEMM (stage 1 only). BT=0: B is [K,N]. 128x128x16, 8x8 micro.
// ---------------------------------------------------------------------------
template <int BT>
__global__ __launch_bounds__(256) void sgemm(
    const float* __restrict__ A, const float* __restrict__ B, float* __restrict__ C,
    int M, int N, int K,
    const float* __restrict__ bias, const float* __restrict__ resid,
    int act, int accumulate) {
  __shared__ float As[16][128];
  __shared__ float Bs[16][128];
  int tid = threadIdx.x;
  int bm0 = blockIdx.x * 128;
  int bn0 = blockIdx.y * 128;
  int tx = tid & 15, ty = tid >> 4;
  float acc[8][8];
#pragma unroll
  for (int i = 0; i < 8; ++i)
#pragma unroll
    for (int j = 0; j < 8; ++j) acc[i][j] = 0.f;

  int ar = tid >> 2;
  int akc = (tid & 3) << 2;
  bool bfull = (bn0 + 127 < N);

  for (int k0 = 0; k0 < K; k0 += 16) {
    {
      const float* ap = A + (i64)(bm0 + ar) * K + k0 + akc;
      float4 a0 = *(const float4*)ap;
      float4 a1 = *(const float4*)(ap + (i64)64 * K);
      As[akc + 0][ar] = a0.x; As[akc + 1][ar] = a0.y;
      As[akc + 2][ar] = a0.z; As[akc + 3][ar] = a0.w;
      As[akc + 0][ar + 64] = a1.x; As[akc + 1][ar + 64] = a1.y;
      As[akc + 2][ar + 64] = a1.z; As[akc + 3][ar + 64] = a1.w;
    }
    if (BT) {
      int br = tid >> 1;
      int bkc = (tid & 1) << 3;
      const float* bp = B + (i64)(bn0 + br) * K + k0 + bkc;
      float4 b0 = *(const float4*)bp;
      float4 b1 = *(const float4*)(bp + 4);
      Bs[bkc + 0][br] = b0.x; Bs[bkc + 1][br] = b0.y;
      Bs[bkc + 2][br] = b0.z; Bs[bkc + 3][br] = b0.w;
      Bs[bkc + 4][br] = b1.x; Bs[bkc + 5][br] = b1.y;
      Bs[bkc + 6][br] = b1.z; Bs[bkc + 7][br] = b1.w;
    } else {
      int bk = tid >> 4;
      int bn = (tid & 15) << 3;
      const float* bp = B + (i64)(k0 + bk) * N + bn0 + bn;
      if (bfull) {
        *(float4*)&Bs[bk][bn] = *(const float4*)bp;
        *(float4*)&Bs[bk][bn + 4] = *(const float4*)(bp + 4);
      } else {
#pragma unroll
        for (int q = 0; q < 8; ++q)
          Bs[bk][bn + q] = (bn0 + bn + q < N) ? bp[q] : 0.f;
      }
    }
    __syncthreads();
#pragma unroll
    for (int kk = 0; kk < 16; ++kk) {
      float a[8], b[8];
      *(float4*)(a)     = *(const float4*)&As[kk][ty * 8];
      *(float4*)(a + 4) = *(const float4*)&As[kk][ty * 8 + 4];
      *(float4*)(b)     = *(const float4*)&Bs[kk][tx * 8];
      *(float4*)(b + 4) = *(const float4*)&Bs[kk][tx * 8 + 4];
#pragma unroll
      for (int i = 0; i < 8; ++i)
#pragma unroll
        for (int j = 0; j < 8; ++j)
          acc[i][j] = fmaf(a[i], b[j], acc[i][j]);
    }
    __syncthreads();
  }
#pragma unroll
  for (int i = 0; i < 8; ++i) {
    int m = bm0 + ty * 8 + i;
#pragma unroll
    for (int j = 0; j < 8; ++j) {
      int n = bn0 + tx * 8 + j;
      if (n < N) {
        i64 ci = (i64)m * N + n;
        float v = acc[i][j];
        if (accumulate) {
          C[ci] += v;
        } else {
          if (bias) v += bias[n];
          if (act == 1) v = v > 0.f ? v : expm1f(v);
          if (resid) v += resid[ci];
          C[ci] = v;
        }
      }
    }
  }
}

// ---------------------------------------------------------------------------
// Stage 2 opener: TAGConv layer 0 (feats in LDS) + residual + BN stats
// ---------------------------------------------------------------------------
__global__ __launch_bounds__(256) void tag_fused(
    const float* __restrict__ hbuf, const float* __restrict__ tag_w,
    const float* __restrict__ tag_b, float* __restrict__ hres,
    float* __restrict__ stats) {
  int b = blockIdx.x, tid = threadIdx.x;
  __shared__ float fe[NPG][FDIM];
  __shared__ float wsh[FDIM * HID];
  __shared__ float S[HID];
  __shared__ float cs[HID], cq[HID];
  if (tid < HID) { cs[tid] = 0.f; cq[tid] = 0.f; }
  const float* hp = hbuf + (i64)b * NPG * HID;
  for (int idx = tid; idx < NPG * HID; idx += 256) fe[idx >> 5][idx & 31] = hp[idx];
  for (int idx = tid; idx < FDIM * HID; idx += 256) wsh[idx] = tag_w[idx];
  __syncthreads();
  if (tid < HID) {
    float s = 0.f;
    for (int p = 0; p < NPG; ++p) s += fe[p][tid];
    S[tid] = s;
  }
  __syncthreads();
  const float wn = 1.f / 22.f;
  for (int idx = tid; idx < NPG * HID; idx += 256) {
    int p = idx >> 5, c = idx & 31;
    float f0 = fe[p][c], Sc = S[c];
    float f1 = (Sc - f0) * wn;
    float f2 = (Sc - f1) * wn;
    float f3 = (Sc - f2) * wn;
    fe[p][HID + c] = f1;
    fe[p][2 * HID + c] = f2;
    fe[p][3 * HID + c] = f3;
  }
  __syncthreads();
  for (int idx = tid; idx < NPG * HID; idx += 256) {
    int p = idx >> 5, c = idx & 31;
    float acc = tag_b[c];
#pragma unroll 8
    for (int k = 0; k < FDIM; ++k) acc += fe[p][k] * wsh[k * HID + c];
    float v = fe[p][c] + acc;
    hres[(i64)(b * NPG + p) * HID + c] = v;
    atomicAdd(&cs[c], v);
    atomicAdd(&cq[c], v * v);
  }
  __syncthreads();
  if (tid < HID) {
    atomicAdd(&stats[tid], cs[tid]);
    atomicAdd(&stats[HID + tid], cq[tid]);
  }
}

// ---------------------------------------------------------------------------
// Stage 2 main: BN-normalize + GAT (layer i) + TAGConv (layer i+1)
// ---------------------------------------------------------------------------
__global__ __launch_bounds__(256) void gat_tag_fused(
    const float* __restrict__ hres, const float* __restrict__ stats,
    const float* __restrict__ gat_w, const float* __restrict__ asrc,
    const float* __restrict__ adst, const float* __restrict__ gbias,
    ushort_t* __restrict__ outseq,
    const float* __restrict__ tag_w_next, const float* __restrict__ tag_b_next,
    float* __restrict__ hres_out, float* __restrict__ stats_next, int has_next) {
  int b = blockIdx.x, tid = threadIdx.x;
  __shared__ float hn[NPG * HID];
  __shared__ float ssrc[NPG * 8], sdst[NPG * 8], sinv[NPG * 8];
  __shared__ float buf[10120];   // A: gsh[5888]+ealpha[4232] | B: fe[2944]+wsh[4096]
  __shared__ float S[HID], cs[HID], cq[HID];
  float* gsh = buf;
  float* ealpha = buf + 5888;
  const float invR = 1.f / (float)NNODES;
  for (int idx = tid; idx < NPG * HID; idx += 256) {
    int c = idx & 31;
    float mu = stats[c] * invR;
    float var = stats[HID + c] * invR - mu * mu;
    hn[idx] = (hres[(i64)b * NPG * HID + idx] - mu) * rsqrtf(var + EPSBN);
  }
  __syncthreads();
  for (int idx = tid; idx < NPG * CDIM; idx += 256) {
    int p = idx >> 8, d = idx & 255;
    float acc = 0.f;
#pragma unroll
    for (int k = 0; k < HID; ++k) acc += hn[p * HID + k] * gat_w[k * CDIM + d];
    gsh[idx] = acc;
  }
  __syncthreads();
  if (tid < NPG * 8) {
    int p = tid >> 3, hd = tid & 7;
    float s1 = 0.f, s2 = 0.f;
    const float* gp = &gsh[p * CDIM + hd * 32];
#pragma unroll
    for (int d = 0; d < 32; ++d) {
      s1 += gp[d] * asrc[hd * 32 + d];
      s2 += gp[d] * adst[hd * 32 + d];
    }
    ssrc[tid] = s1;
    sdst[tid] = s2;
  }
  __syncthreads();
  if (tid < NPG * 8) {
    int v = tid >> 3, hd = tid & 7;
    float sd = sdst[v * 8 + hd];
    float e[NPG];
    float m = -1e30f;
#pragma unroll
    for (int u = 0; u < NPG; ++u) {
      float xv = ssrc[u * 8 + hd] + sd;
      xv = xv > 0.f ? xv : 0.2f * xv;
      e[u] = xv;
      m = fmaxf(m, xv);
    }
    float s = 0.f;
#pragma unroll
    for (int u = 0; u < NPG; ++u) {
      float t = __expf(e[u] - m);
      ealpha[(v * NPG + u) * 8 + hd] = t;
      s += t;
    }
    sinv[tid] = 1.f / s;
  }
  __syncthreads();
  {
    int hd = tid >> 5, d = tid & 31;
    const i64 base = (i64)b * NPG * CDIM;
    for (int v = 0; v < NPG; ++v) {
      float acc = 0.f;
#pragma unroll
      for (int u = 0; u < NPG; ++u)
        acc += ealpha[(v * NPG + u) * 8 + hd] * gsh[u * CDIM + hd * 32 + d];
      outseq[base + (i64)v * CDIM + hd * 32 + d] =
          f2bf(acc * sinv[v * 8 + hd] + gbias[hd * 32 + d]);
    }
  }
  if (!has_next) return;
  __syncthreads();
  float* fe = buf;
  float* wsh = buf + 2944;
  if (tid < HID) { cs[tid] = 0.f; cq[tid] = 0.f; }
  for (int idx = tid; idx < FDIM * HID; idx += 256) wsh[idx] = tag_w_next[idx];
  for (int idx = tid; idx < NPG * HID; idx += 256)
    fe[(idx >> 5) * FDIM + (idx & 31)] = hn[idx];
  __syncthreads();
  if (tid < HID) {
    float s = 0.f;
    for (int p = 0; p < NPG; ++p) s += fe[p * FDIM + tid];
    S[tid] = s;
  }
  __syncthreads();
  const float wn = 1.f / 22.f;
  for (int idx = tid; idx < NPG * HID; idx += 256) {
    int p = idx >> 5, c = idx & 31;
    float f0 = fe[p * FDIM + c], Sc = S[c];
    float f1 = (Sc - f0) * wn;
    float f2 = (Sc - f1) * wn;
    float f3 = (Sc - f2) * wn;
    fe[p * FDIM + HID + c] = f1;
    fe[p * FDIM + 2 * HID + c] = f2;
    fe[p * FDIM + 3 * HID + c] = f3;
  }
  __syncthreads();
  for (int idx = tid; idx < NPG * HID; idx += 256) {
    int p = idx >> 5, c = idx & 31;
    float acc = tag_b_next[c];
#pragma unroll 8
    for (int k = 0; k < FDIM; ++k) acc += fe[p * FDIM + k] * wsh[k * HID + c];
    float v = fe[p * FDIM + c] + acc;
    hres_out[(i64)(b * NPG + p) * HID + c] = v;
    atomicAdd(&cs[c], v);
    atomicAdd(&cq[c], v * v);
  }
  __syncthreads();
  if (tid < HID) {
    atomicAdd(&stats_next[tid], cs[tid]);
    atomicAdd(&stats_next[HID + tid], cq[tid]);
  }
}

// ---------------------------------------------------------------------------
// weight packing (LSTM): row g*896+j -> packed row p=(j>>4)*64+g*16+(j&15)
// ---------------------------------------------------------------------------
__global__ void pack_w(const float* __restrict__ w, ushort_t* __restrict__ wp,
                       int ldK) {
  i64 total = (i64)ZCOLS * ldK;
  i64 idx = (i64)blockIdx.x * 256 + threadIdx.x;
  i64 stride = (i64)gridDim.x * 256;
  for (; idx < total; idx += stride) {
    int r = (int)(idx / ldK), k = (int)(idx % ldK);
    int g = r / JKH, jj = r % JKH;
    int p = (jj >> 4) * 64 + g * 16 + (jj & 15);
    wp[(i64)p * ldK + k] = f2bf(w[idx]);
  }
}

__global__ void pack_b(const float* __restrict__ a, const float* __restrict__ b,
                       float* __restrict__ bp) {
  int r = blockIdx.x * 256 + threadIdx.x;
  if (r < ZCOLS) {
    int g = r / JKH, jj = r % JKH;
    int p = (jj >> 4) * 64 + g * 16 + (jj & 15);
    bp[p] = a[r] + b[r];
  }
}

// transpose-pack: w [K,N] fp32 -> wt [N,K] bf16
__global__ void pack_t(const float* __restrict__ w, ushort_t* __restrict__ wt,
                       int K, int N) {
  i64 total = (i64)K * N;
  i64 idx = (i64)blockIdx.x * 256 + threadIdx.x;
  i64 stride = (i64)gridDim.x * 256;
  for (; idx < total; idx += stride) {
    int k = (int)(idx / N), n = (int)(idx % N);
    wt[(i64)n * K + k] = f2bf(w[idx]);
  }
}

// ---------------------------------------------------------------------------
// Fused LSTM step + JK attention dot (LDS-pre-reduced, fast-exp epilogue)
// ---------------------------------------------------------------------------
template <int HASH>
__global__ __launch_bounds__(256) void lstm_step(
    const ushort_t* __restrict__ Aseq,   // [rows,256] bf16
    const ushort_t* __restrict__ Wih,    // [3584,256] bf16 packed
    const ushort_t* __restrict__ Hprev,  // [rows,896] bf16
    const ushort_t* __restrict__ Whh,    // [3584,896] bf16 packed
    const float*  __restrict__ bspk,     // [3584] packed bias
    float* __restrict__ Cst,             // [rows,896] fp32 (in-place)
    ushort_t* __restrict__ Hout,         // [rows,896] bf16
    const float* __restrict__ jkw,       // [896]
    float* __restrict__ attp) {          // [rows] atomic accum
  __shared__ ushort_t As[128 * 64];
  __shared__ ushort_t Bs[128 * 64];
  __shared__ float att_s[128];
  int tid = threadIdx.x;
  int w = tid >> 6, lane = tid & 63;
  int m0 = blockIdx.x * 128;
  int n0 = blockIdx.y * 128;
  f32x4 acc[4][4];
#pragma unroll
  for (int a = 0; a < 4; ++a)
#pragma unroll
    for (int b = 0; b < 4; ++b) acc[a][b] = (f32x4){0.f, 0.f, 0.f, 0.f};

  const ushort_t* aptr = Aseq;
  const ushort_t* bptr = Wih;
  int lda = CDIM, K = CDIM;
  for (int phase = 0; phase < (HASH ? 2 : 1); ++phase) {
    for (int k0 = 0; k0 < K; k0 += 64) {
#pragma unroll
      for (int i = 0; i < 4; ++i) {
        int r = w + i * 4;
        int s = r * 64 + lane;
        int row = s >> 3;
        int kc = (s & 7) ^ (row & 7);
        gload16(aptr + (i64)(m0 + row) * lda + k0 + kc * 8, &As[r * 512]);
        gload16(bptr + (i64)(n0 + row) * lda + k0 + kc * 8, &Bs[r * 512]);
      }
      __syncthreads();
#pragma unroll
      for (int ks = 0; ks < 2; ++ks) {
        bf16x8 af[4], bfr[4];
        int kq = ks * 4 + (lane >> 4);
#pragma unroll
        for (int mi = 0; mi < 4; ++mi) {
          int row = (w & 1) * 64 + mi * 16 + (lane & 15);
          int pos = row * 8 + (kq ^ (row & 7));
          af[mi] = *(const bf16x8*)&As[pos * 8];
        }
#pragma unroll
        for (int ni = 0; ni < 4; ++ni) {
          int row = (w >> 1) * 64 + ni * 16 + (lane & 15);
          int pos = row * 8 + (kq ^ (row & 7));
          bfr[ni] = *(const bf16x8*)&Bs[pos * 8];
        }
#pragma unroll
        for (int mi = 0; mi < 4; ++mi)
#pragma unroll
          for (int ni = 0; ni < 4; ++ni)
            acc[mi][ni] = __builtin_amdgcn_mfma_f32_16x16x32_bf16(
                af[mi], bfr[ni], acc[mi][ni], 0, 0, 0);
      }
      __syncthreads();
    }
    aptr = Hprev; bptr = Whh; lda = JKH; K = JKH;
  }

  if (tid < 128) att_s[tid] = 0.f;
  __syncthreads();

  int jb = (n0 >> 6) + (w >> 1);
  int j = jb * 16 + (lane & 15);
  float jw = jkw[j];
  float bsi = bspk[jb * 64 + (lane & 15)];
  float bsf = bspk[jb * 64 + 16 + (lane & 15)];
  float bsg = bspk[jb * 64 + 32 + (lane & 15)];
  float bso = bspk[jb * 64 + 48 + (lane & 15)];
#pragma unroll
  for (int mi = 0; mi < 4; ++mi) {
#pragma unroll
    for (int reg = 0; reg < 4; ++reg) {
      int mloc = (w & 1) * 64 + mi * 16 + (lane >> 4) * 4 + reg;
      int m = m0 + mloc;
      float zi = acc[mi][0][reg] + bsi;
      float zf = acc[mi][1][reg] + bsf;
      float zg = acc[mi][2][reg] + bsg;
      float zo = acc[mi][3][reg] + bso;
      i64 ci = (i64)m * JKH + j;
      float cv = fsig(zi) * ftanh(zg);
      if (HASH) cv += fsig(zf) * Cst[ci];
      Cst[ci] = cv;
      float hv = fsig(zo) * ftanh(cv);
      Hout[ci] = f2bf(hv);
      float av = hv * jw;
      av += __shfl_xor(av, 1, 64);
      av += __shfl_xor(av, 2, 64);
      av += __shfl_xor(av, 4, 64);
      av += __shfl_xor(av, 8, 64);
      if ((lane & 15) == 0) atomicAdd(&att_s[mloc], av);
    }
  }
  __syncthreads();
  if (tid < 128) atomicAdd(&attp[m0 + tid], att_s[tid]);
}

// ---------------------------------------------------------------------------
// bf16 MFMA GEMM (stage 4): C = [elu](A@Bt^T + bias) [+resid] [+col-stats]
// ---------------------------------------------------------------------------
template <int ACT, int BF16OUT, int STATS>
__global__ __launch_bounds__(256) void mfma_gemm(
    const ushort_t* __restrict__ A, const ushort_t* __restrict__ Bt, int K,
    const float* __restrict__ bias, const float* __restrict__ resid,
    float* __restrict__ Cf, ushort_t* __restrict__ Cb, int N,
    float* __restrict__ stats) {
  __shared__ ushort_t As[128 * 64];
  __shared__ ushort_t Bs[128 * 64];
  __shared__ float cs[128], cq[128];
  int tid = threadIdx.x;
  int w = tid >> 6, lane = tid & 63;
  int m0 = blockIdx.x * 128;
  int n0 = blockIdx.y * 128;
  f32x4 acc[4][4];
#pragma unroll
  for (int a = 0; a < 4; ++a)
#pragma unroll
    for (int b = 0; b < 4; ++b) acc[a][b] = (f32x4){0.f, 0.f, 0.f, 0.f};

  for (int k0 = 0; k0 < K; k0 += 64) {
#pragma unroll
    for (int i = 0; i < 4; ++i) {
      int r = w + i * 4;
      int s = r * 64 + lane;
      int row = s >> 3;
      int kc = (s & 7) ^ (row & 7);
      gload16(A + (i64)(m0 + row) * K + k0 + kc * 8, &As[r * 512]);
      gload16(Bt + (i64)(n0 + row) * K + k0 + kc * 8, &Bs[r * 512]);
    }
    __syncthreads();
#pragma unroll
    for (int ks = 0; ks < 2; ++ks) {
      bf16x8 af[4], bfr[4];
      int kq = ks * 4 + (lane >> 4);
#pragma unroll
      for (int mi = 0; mi < 4; ++mi) {
        int row = (w & 1) * 64 + mi * 16 + (lane & 15);
        int pos = row * 8 + (kq ^ (row & 7));
        af[mi] = *(const bf16x8*)&As[pos * 8];
      }
#pragma unroll
      for (int ni = 0; ni < 4; ++ni) {
        int row = (w >> 1) * 64 + ni * 16 + (lane & 15);
        int pos = row * 8 + (kq ^ (row & 7));
        bfr[ni] = *(const bf16x8*)&Bs[pos * 8];
      }
#pragma unroll
      for (int mi = 0; mi < 4; ++mi)
#pragma unroll
        for (int ni = 0; ni < 4; ++ni)
          acc[mi][ni] = __builtin_amdgcn_mfma_f32_16x16x32_bf16(
              af[mi], bfr[ni], acc[mi][ni], 0, 0, 0);
    }
    __syncthreads();
  }
  if (STATS) {
    if (tid < 128) { cs[tid] = 0.f; cq[tid] = 0.f; }
    __syncthreads();
  }
#pragma unroll
  for (int ni = 0; ni < 4; ++ni) {
    int nloc = (w >> 1) * 64 + ni * 16 + (lane & 15);
    int n = n0 + nloc;
    float bv = bias[n];
    float s = 0.f, q = 0.f;
#pragma unroll
    for (int mi = 0; mi < 4; ++mi) {
#pragma unroll
      for (int reg = 0; reg < 4; ++reg) {
        int m = m0 + (w & 1) * 64 + mi * 16 + (lane >> 4) * 4 + reg;
        float v = acc[mi][ni][reg] + bv;
        if (ACT) v = v > 0.f ? v : expm1f(v);
        i64 ci = (i64)m * N + n;
        if (BF16OUT) Cb[ci] = f2bf(v);
        else {
          v += resid[ci];
          Cf[ci] = v;
          if (STATS) { s += v; q += v * v; }
        }
      }
    }
    if (STATS) { atomicAdd(&cs[nloc], s); atomicAdd(&cq[nloc], q); }
  }
  if (STATS) {
    __syncthreads();
    if (tid < 128) {
      atomicAdd(&stats[n0 + tid], cs[tid]);
      atomicAdd(&stats[N + n0 + tid], cq[tid]);
    }
  }
}

// softmax over the 5 layers, weighted sum of bf16 seq -> xg (fp32 + bf16)
__global__ __launch_bounds__(256) void jk_combine(const float* __restrict__ att,
                                                  const ushort_t* __restrict__ seq,
                                                  float* __restrict__ xg,
                                                  ushort_t* __restrict__ xgb) {
  int n = blockIdx.x, c = threadIdx.x;
  float a[5];
  float m = -1e30f;
#pragma unroll
  for (int t = 0; t < 5; ++t) {
    a[t] = att[(i64)t * NNODES + n] + att[(i64)(5 + t) * NNODES + n];
    m = fmaxf(m, a[t]);
  }
  float s = 0.f;
#pragma unroll
  for (int t = 0; t < 5; ++t) { a[t] = __expf(a[t] - m); s += a[t]; }
  float inv = 1.f / s;
  float acc = 0.f;
#pragma unroll
  for (int t = 0; t < 5; ++t)
    acc += bf2f(seq[((i64)t * NNODES + n) * CDIM + c]) * (a[t] * inv);
  xg[(i64)n * CDIM + c] = acc;
  xgb[(i64)n * CDIM + c] = f2bf(acc);
}

__global__ void fill0(float* __restrict__ p, i64 nfloat) {
  i64 i = (i64)blockIdx.x * 256 + threadIdx.x;
  i64 stride = (i64)gridDim.x * 256;
  for (; i < nfloat; i += stride) p[i] = 0.f;
}

// gate vector fold
__global__ __launch_bounds__(256) void fold_gate(
    const float* __restrict__ w1, const float* __restrict__ b1,
    const float* __restrict__ w2, const float* __restrict__ b2,
    float* __restrict__ v, float* __restrict__ b0) {
  int tid = threadIdx.x;
  float s = 0.f;
  for (int j = 0; j < 672; ++j) s += w1[tid * 672 + j] * w2[j];
  v[tid] = s;
  float p = 0.f;
  for (int j = tid; j < 672; j += 256) p += b1[j] * w2[j];
  __shared__ float sh[4];
#pragma unroll
  for (int o = 32; o > 0; o >>= 1) p += __shfl_down(p, o, 64);
  if ((tid & 63) == 0) sh[tid >> 6] = p;
  __syncthreads();
  if (tid == 0) b0[0] = sh[0] + sh[1] + sh[2] + sh[3] + b2[0];
}

// GlobalAttention pooling per graph (BN-normalize fused; reads raw s4 + stats)
__global__ __launch_bounds__(256) void pool_kernel(
    const float* __restrict__ s4, const float* __restrict__ st,
    const float* __restrict__ v, const float* __restrict__ b0,
    float* __restrict__ pooled) {
  int g = blockIdx.x, tid = threadIdx.x;
  __shared__ float xn[NPG][CDIM];
  __shared__ float gw[NPG];
  __shared__ float sh[4];
  const float invR = 1.f / (float)NNODES;
  float mu = st[tid] * invR;
  float var = st[CDIM + tid] * invR - mu * mu;
  float rs = rsqrtf(var + EPSBN);
  for (int p = 0; p < NPG; ++p)
    xn[p][tid] = (s4[(i64)(g * NPG + p) * CDIM + tid] - mu) * rs;
  __syncthreads();
  float myv = v[tid];
  for (int p = 0; p < NPG; ++p) {
    float val = xn[p][tid] * myv;
#pragma unroll
    for (int o = 32; o > 0; o >>= 1) val += __shfl_down(val, o, 64);
    if ((tid & 63) == 0) sh[tid >> 6] = val;
    __syncthreads();
    if (tid == 0) gw[p] = sh[0] + sh[1] + sh[2] + sh[3] + b0[0];
    __syncthreads();
  }
  if (tid == 0) {
    float m = -1e30f;
    for (int p = 0; p < NPG; ++p) m = fmaxf(m, gw[p]);
    float s = 0.f;
    for (int p = 0; p < NPG; ++p) { gw[p] = __expf(gw[p] - m); s += gw[p]; }
    float inv = 1.f / s;
    for (int p = 0; p < NPG; ++p) gw[p] *= inv;
  }
  __syncthreads();
  float acc = 0.f;
  for (int p = 0; p < NPG; ++p) acc += gw[p] * xn[p][tid];
  pooled[(i64)g * CDIM + tid] = acc;
}

__global__ void fold_conv2(const float* __restrict__ w, const float* __restrict__ b,
                           float* __restrict__ wbar) {
  int tid = threadIdx.x;
  if (tid < 9) {
    float s = 0.f;
    for (int o = 0; o < 10; ++o) s += w[o * 9 + tid];
    wbar[tid] = s * 0.1f;
  } else if (tid == 9) {
    float s = 0.f;
    for (int o = 0; o < 10; ++o) s += b[o];
    wbar[9] = s * 0.1f;
  }
}

__global__ __launch_bounds__(256) void conv2mean(const float* __restrict__ pooled,
                                                 const float* __restrict__ wbar,
                                                 float* __restrict__ y2) {
  int b = blockIdx.x, h = threadIdx.x;
  __shared__ float row[CDIM];
  row[h] = pooled[(i64)b * CDIM + h];
  __syncthreads();
  float s = wbar[9];
#pragma unroll
  for (int t = 0; t < 9; ++t) {
    int hh = h + t - 4;
    if (hh >= 0 && hh < CDIM) s += row[hh] * wbar[t];
  }
  y2[(i64)b * CDIM + h] = s;
}

__global__ __launch_bounds__(256) void final_fc(
    const float* __restrict__ y2, const float* __restrict__ acc,
    const float* __restrict__ g2, const float* __restrict__ b2,
    const float* __restrict__ fcw, const float* __restrict__ fcb,
    float* __restrict__ out) {
  int b = blockIdx.x, tid = threadIdx.x;
  __shared__ float yn[CDIM];
  __shared__ float logits[10];
  __shared__ float red[2];
  float mu = acc[tid] / 512.f;
  float var = acc[CDIM + tid] / 512.f - mu * mu;
  yn[tid] = (y2[(i64)b * CDIM + tid] - mu) * rsqrtf(var + EPSBN) * g2[tid] + b2[tid];
  __syncthreads();
  if (tid < 10) {
    float s = fcb[tid];
    for (int h = 0; h < CDIM; ++h) s += yn[h] * fcw[h * 10 + tid];
    logits[tid] = s;
  }
  __syncthreads();
  if (tid == 0) {
    float m = -1e30f;
    for (int o = 0; o < 10; ++o) m = fmaxf(m, logits[o]);
    float s = 0.f;
    for (int o = 0; o < 10; ++o) s += expf(logits[o] - m);
    red[0] = m;
    red[1] = logf(s);
  }
  __syncthreads();
  if (tid < 10) out[(i64)b * 10 + tid] = logits[tid] - red[0] - red[1];
}

// ---------------------------------------------------------------------------
extern "C" void kernel_launch(void* const* d_in, const int* in_sizes, int n_in,
                              void* d_out, int out_size, void* d_ws, size_t ws_size,
                              hipStream_t stream) {
  (void)in_sizes; (void)n_in; (void)out_size;
  const float* x        = (const float*)d_in[0];
  const float* conv1_w  = (const float*)d_in[4];
  const float* conv1_b  = (const float*)d_in[5];
  const float* bn1_g    = (const float*)d_in[6];
  const float* bn1_b    = (const float*)d_in[7];
  const float* ll1_w    = (const float*)d_in[8];
  const float* ll1_b    = (const float*)d_in[9];
  const float* tag_w    = (const float*)d_in[10];
  const float* tag_b    = (const float*)d_in[11];
  const float* gat_w    = (const float*)d_in[12];
  const float* gat_asrc = (const float*)d_in[13];
  const float* gat_adst = (const float*)d_in[14];
  const float* gat_b    = (const float*)d_in[15];
  const float* lw_ih[2] = {(const float*)d_in[16], (const float*)d_in[20]};
  const float* lw_hh[2] = {(const float*)d_in[17], (const float*)d_in[21]};
  const float* lb_ih[2] = {(const float*)d_in[18], (const float*)d_in[22]};
  const float* lb_hh[2] = {(const float*)d_in[19], (const float*)d_in[23]};
  const float* jk_w     = (const float*)d_in[24];
  const float* fff_w1   = (const float*)d_in[26];
  const float* fff_b1   = (const float*)d_in[27];
  const float* fff_w2   = (const float*)d_in[28];
  const float* fff_b2   = (const float*)d_in[29];
  const float* gate_w1  = (const float*)d_in[30];
  const float* gate_b1  = (const float*)d_in[31];
  const float* gate_w2  = (const float*)d_in[32];
  const float* gate_b2  = (const float*)d_in[33];
  const float* conv2_w  = (const float*)d_in[34];
  const float* conv2_b  = (const float*)d_in[35];
  const float* bn2_g    = (const float*)d_in[36];
  const float* bn2_b    = (const float*)d_in[37];
  const float* fc_w     = (const float*)d_in[38];
  const float* fc_b     = (const float*)d_in[39];
  float* out = (float*)d_out;

  float* ws = (float*)d_ws;
  i64 off = 0;
  auto alloc = [&](i64 n) { float* p = ws + off; off += (n + 15) & ~(i64)15; return p; };
  ushort_t* seqb = (ushort_t*)alloc(7536640);       // 5*N*256 bf16
  // zero-initialized region (one fill0): att + all stats buffers
  float* att = alloc(10 * NNODES);
  float* st1 = alloc(256);
  float* st2 = alloc(6 * 64);
  float* st4 = alloc(512);
  float* st5 = alloc(512);
  i64 zcount = (i64)(st5 - att) + 512;
  float* xg     = alloc((i64)NNODES * CDIM);
  ushort_t* xgb = (ushort_t*)alloc((i64)NNODES * CDIM / 2);
  float* hbuf   = alloc((i64)NNODES * HID);
  float* hres   = alloc((i64)NNODES * HID);
  float* Wp     = alloc(FDIM * HID);
  float* bp     = alloc(64);
  ushort_t* wihb[2]; ushort_t* whhb[2]; float* bspk[2];
  for (int d = 0; d < 2; ++d) {
    wihb[d] = (ushort_t*)alloc((i64)ZCOLS * CDIM / 2);
    whhb[d] = (ushort_t*)alloc((i64)ZCOLS * JKH / 2);
    bspk[d] = alloc(ZCOLS);
  }
  ushort_t* w1t = (ushort_t*)alloc(512 * 256 / 2);
  ushort_t* w2t = (ushort_t*)alloc(256 * 512 / 2);
  float* gatev  = alloc(CDIM);
  float* gateb0 = alloc(16);
  float* wbar   = alloc(16);
  float* pooled = alloc((i64)NGR * CDIM);
  float* y2     = alloc((i64)NGR * CDIM);
  float* Zs = ws + off;                              // shared overlay region
  i64 S = (i64)(ws_size / 4) - off;
  if (S < 0) S = 0;

  // LSTM chunk: per 128-row tile: hA 28672 + hB 28672 + c 114688 = 172032 floats
  int Tch = (int)(S / 172032); if (Tch < 1) Tch = 1; if (Tch > 92) Tch = 92;
  // stage-4: s4 = 3,014,656 floats; ff1b tile = 128*512 bf16 = 32768 float-equiv
  i64 Sff = S - 3014656;
  int Tf = (int)(Sff / 32768); if (Tf < 1) Tf = 1; if (Tf > 92) Tf = 92;

  // overlays (disjoint lifetimes)
  float* xconv = Zs;                                  // [N,128] stage 1
  ushort_t* hA = (ushort_t*)Zs;                       // [Tch*128,896] bf16
  ushort_t* hB = hA + (i64)Tch * 128 * JKH;
  float* cch   = (float*)(hB + (i64)Tch * 128 * JKH); // [Tch*128,896] fp32
  float* s4  = Zs;                                    // [N,256] stage 4
  ushort_t* ff1b = (ushort_t*)(s4 + 3014656);         // [Tf*128,512] bf16

  // ---- zero att+stats; pack weights ----
  fill0<<<512, 256, 0, stream>>>(att, zcount);
  for (int d = 0; d < 2; ++d) {
    pack_w<<<2048, 256, 0, stream>>>(lw_ih[d], wihb[d], CDIM);
    pack_w<<<4096, 256, 0, stream>>>(lw_hh[d], whhb[d], JKH);
    pack_b<<<14, 256, 0, stream>>>(lb_ih[d], lb_hh[d], bspk[d]);
  }
  pack_t<<<512, 256, 0, stream>>>(fff_w1, w1t, CDIM, 512);
  pack_t<<<512, 256, 0, stream>>>(fff_w2, w2t, 512, CDIM);

  // ---- stage 1: PE + conv1 (+stats) + BN1-fold + ll1 ----
  conv1_kernel<<<NGR, 256, 0, stream>>>(x, conv1_w, conv1_b, xconv, st1);
  fold_ll1<<<1, 256, 0, stream>>>(st1, bn1_g, bn1_b, ll1_w, ll1_b, Wp, bp);
  sgemm<0><<<dim3(92, 1), 256, 0, stream>>>(xconv, Wp, hbuf, NNODES, HID, FDIM,
                                            bp, nullptr, 0, 0);

  // ---- stage 2: tag layer0, then 5x fused GAT(i)+TAG(i+1) ----
  tag_fused<<<NGR, 256, 0, stream>>>(hbuf, tag_w, tag_b, hres, st2);
  for (int i = 0; i < 5; ++i) {
    int nx = (i < 4) ? (i + 1) : 0;
    gat_tag_fused<<<NGR, 256, 0, stream>>>(
        hres, st2 + i * 64, gat_w + (i64)i * HID * CDIM,
        gat_asrc + i * 256, gat_adst + i * 256, gat_b + i * 256,
        seqb + (i64)i * NNODES * CDIM,
        tag_w + (i64)nx * FDIM * HID, tag_b + nx * HID,
        hres, st2 + (i + 1) * 64, (i < 4) ? 1 : 0);
  }

  // ---- stage 3: bi-LSTM, fused MFMA steps + att dot, row-chunked ----
  for (int dir = 0; dir < 2; ++dir) {
    for (int t0 = 0; t0 < 92; t0 += Tch) {
      int tiles = (92 - t0 < Tch) ? (92 - t0) : Tch;
      i64 r0 = (i64)t0 * 128;
      ushort_t* hp[2] = {hA, hB};
      for (int t = 0; t < 5; ++t) {
        int ts = dir ? 4 - t : t;
        const ushort_t* Ax = seqb + ((i64)ts * NNODES + r0) * CDIM;
        float* attp = att + (i64)(dir * 5 + ts) * NNODES + r0;
        if (t == 0)
          lstm_step<0><<<dim3(tiles, 28), 256, 0, stream>>>(
              Ax, wihb[dir], nullptr, nullptr, bspk[dir], cch, hp[0],
              jk_w + dir * JKH, attp);
        else
          lstm_step<1><<<dim3(tiles, 28), 256, 0, stream>>>(
              Ax, wihb[dir], hp[(t + 1) & 1], whhb[dir], bspk[dir], cch, hp[t & 1],
              jk_w + dir * JKH, attp);
      }
    }
  }
  jk_combine<<<NNODES, 256, 0, stream>>>(att, seqb, xg, xgb);

  // ---- stage 4: FFF (bf16 MFMA, stats fused) ----
  for (int t0 = 0; t0 < 92; t0 += Tf) {
    int tiles = (92 - t0 < Tf) ? (92 - t0) : Tf;
    i64 r0 = (i64)t0 * 128;
    mfma_gemm<1, 1, 0><<<dim3(tiles, 4), 256, 0, stream>>>(
        xgb + r0 * CDIM, w1t, CDIM, fff_b1, nullptr, nullptr, ff1b, 512, nullptr);
    mfma_gemm<0, 0, 1><<<dim3(tiles, 2), 256, 0, stream>>>(
        ff1b, w2t, 512, fff_b2, xg + r0 * CDIM, s4 + r0 * CDIM, nullptr, CDIM, st4);
  }

  // ---- stage 5: pool (BN fused) + conv2/mean + BN2 + fc + log_softmax ----
  fold_gate<<<1, 256, 0, stream>>>(gate_w1, gate_b1, gate_w2, gate_b2, gatev, gateb0);
  pool_kernel<<<NGR, 256, 0, stream>>>(s4, st4, gatev, gateb0, pooled);
  fold_conv2<<<1, 64, 0, stream>>>(conv2_w, conv2_b, wbar);
  conv2mean<<<NGR, 256, 0, stream>>>(pooled, wbar, y2);
  col_stats<<<64, 256, 0, stream>>>(y2, NGR, CDIM, st5);
  final_fc<<<NGR, 256, 0, stream>>>(y2, st5, bn2_g, bn2_b, fc_w, fc_b, out);
}